// Round 1
// 610.824 us; speedup vs baseline: 1.0140x; 1.0140x over previous
//
#include <hip/hip_runtime.h>
#include <hip/hip_bf16.h>
#include <stdint.h>

typedef __hip_bfloat16 bf16;
typedef __attribute__((ext_vector_type(8))) short s16x8;
typedef __attribute__((ext_vector_type(4))) float f32x4;

#define B_   2
#define S_   2048
#define D_   1024
#define H_   16
#define HD_  64
#define FFD_ 4096
#define M_   4096
#define MEG  ((size_t)1048576)

__device__ __forceinline__ f32x4 mfma_bf16(s16x8 a, s16x8 b, f32x4 c) {
  return __builtin_amdgcn_mfma_f32_16x16x32_bf16(a, b, c, 0, 0, 0);
}

__device__ __forceinline__ void gl_lds16(const bf16* g, bf16* l) {
  __builtin_amdgcn_global_load_lds(
      (const __attribute__((address_space(1))) void*)g,
      (__attribute__((address_space(3))) void*)l, 16, 0, 0);
}

__device__ __forceinline__ float b2f(short u) {
  union { uint32_t i; float f; } z;
  z.i = ((uint32_t)(unsigned short)u) << 16;
  return z.f;
}
__device__ __forceinline__ short f2b(float f) {
  const bf16 h = __float2bfloat16(f);
  return *(const short*)&h;
}

// ---------------------------------------------------------------------------
// fp32 -> bf16 conversion (inputs are fp32; GEMM operands need bf16).
// ---------------------------------------------------------------------------
__global__ __launch_bounds__(256) void cvt_f2b(
    const float* __restrict__ src, bf16* __restrict__ dst, int n) {
  const int idx = (blockIdx.x * 256 + threadIdx.x) * 8;
  if (idx >= n) return;
  s16x8 o;
#pragma unroll
  for (int i = 0; i < 8; ++i) o[i] = f2b(src[idx + i]);
  *(s16x8*)(dst + idx) = o;
}

// ---------------------------------------------------------------------------
// MFMA NT GEMM: C[m,n] = sum_k A[m,k]*W[n,k] + bias[n]  (bias fp32)
// 128x128 tile, BK=32, 4 waves (2x2), 4x4 16x16x32 frags.
// MODE 0: C -> bf16 Cb             (out-proj -> y1)
// MODE 1: relu, C -> bf16 Cb       (MLP1 -> ff)
// MODE 2: C + resid(bf16) -> fp32 Cf  (MLP2 -> sum in d_out)
// MODE 3: QKV split: seg0 q->bf16 Cb; seg1 k->fp32 Kf + bf16 Kb;
//         seg2 v->fp32 Vf + bf16 Vb.  All row stride 1024.
// ---------------------------------------------------------------------------
template <int MODE>
__global__ __launch_bounds__(256) void gemm_bt(
    const bf16* __restrict__ A, const bf16* __restrict__ W,
    const float* __restrict__ bias,
    bf16* __restrict__ Cb, float* __restrict__ Cf,
    float* __restrict__ Kf, bf16* __restrict__ Kb,
    float* __restrict__ Vf, bf16* __restrict__ Vb,
    const bf16* __restrict__ Res,
    int M, int N, int K) {
  __shared__ __align__(16) bf16 As[128 * 32];
  __shared__ __align__(16) bf16 Bs[128 * 32];
  const int t = threadIdx.x;
  const int m0 = blockIdx.y << 7, n0 = blockIdx.x << 7;
  const int w = t >> 6, l = t & 63;
  const int wm = (w >> 1) << 6, wn = (w & 1) << 6;
  const int l15 = l & 15, quad = l >> 4;

  f32x4 acc[4][4] = {};

  const int srow = t >> 2;          // 0..63
  const int scol = (t & 3) << 3;    // 0,8,16,24
  const bf16* Ag  = A + (size_t)(m0 + srow) * K + scol;
  const bf16* Ag2 = Ag + ((size_t)K << 6);   // +64 rows
  const bf16* Wg  = W + (size_t)(n0 + srow) * K + scol;
  const bf16* Wg2 = Wg + ((size_t)K << 6);
  bf16* Al  = As + t * 8;
  bf16* Al2 = Al + 2048;
  bf16* Bl  = Bs + t * 8;
  bf16* Bl2 = Bl + 2048;

  for (int k0 = 0; k0 < K; k0 += 32) {
    __syncthreads();
    gl_lds16(Ag + k0, Al);
    gl_lds16(Ag2 + k0, Al2);
    gl_lds16(Wg + k0, Bl);
    gl_lds16(Wg2 + k0, Bl2);
    __syncthreads();
    const s16x8* As8 = (const s16x8*)As;
    const s16x8* Bs8 = (const s16x8*)Bs;
    s16x8 af[4], bfr[4];
#pragma unroll
    for (int i = 0; i < 4; ++i) af[i]  = As8[((wm + i * 16 + l15) << 2) + quad];
#pragma unroll
    for (int i = 0; i < 4; ++i) bfr[i] = Bs8[((wn + i * 16 + l15) << 2) + quad];
#pragma unroll
    for (int mi = 0; mi < 4; ++mi)
#pragma unroll
      for (int ni = 0; ni < 4; ++ni)
        acc[mi][ni] = mfma_bf16(af[mi], bfr[ni], acc[mi][ni]);
  }

  float bv[4];
#pragma unroll
  for (int ni = 0; ni < 4; ++ni)
    bv[ni] = bias[n0 + wn + ni * 16 + l15];

  const int seg = n0 >> 10, nb = n0 & 1023;
#pragma unroll
  for (int mi = 0; mi < 4; ++mi) {
#pragma unroll
    for (int reg = 0; reg < 4; ++reg) {
      const int row = m0 + wm + mi * 16 + quad * 4 + reg;
#pragma unroll
      for (int ni = 0; ni < 4; ++ni) {
        float v = acc[mi][ni][reg] + bv[ni];
        if (MODE == 0) {
          Cb[(size_t)row * N + n0 + wn + ni * 16 + l15] = __float2bfloat16(v);
        } else if (MODE == 1) {
          v = fmaxf(v, 0.f);
          Cb[(size_t)row * N + n0 + wn + ni * 16 + l15] = __float2bfloat16(v);
        } else if (MODE == 2) {
          const size_t o = (size_t)row * N + n0 + wn + ni * 16 + l15;
          Cf[o] = v + b2f(*(const short*)&Res[o]);
        } else {  // MODE 3
          const size_t o = (size_t)row * 1024 + nb + wn + ni * 16 + l15;
          if (seg == 0) {
            Cb[o] = __float2bfloat16(v);
          } else if (seg == 1) {
            Kf[o] = v; Kb[o] = __float2bfloat16(v);
          } else {
            Vf[o] = v; Vb[o] = __float2bfloat16(v);
          }
        }
      }
    }
  }
}

// ---------------------------------------------------------------------------
// MFMA flash attention, causal, hd=64. Block = (64 q-rows, head, batch).
// Q/K/V: bf16 [M,1024] ws buffers. O: bf16 [M,1024].
// v2: XOR chunk-swizzle on Ks/Vt/Ps (kills 16-way ds_read_b128 conflicts),
//     K/V double-buffer with 1 barrier per k-tile (was 3), T14 split V
//     staging (load-early / ds_write-late), reversed qt dispatch (long
//     blocks first to fix the causal tail imbalance).
// Swizzle: phys_elem_col = log_col ^ ((row & 7) << 3)  within each 128B row.
// K is staged by global_load_lds (linear LDS dest) -> swizzle applied by
// pre-permuting the global SOURCE chunk (rule: both-sides-or-neither).
// ---------------------------------------------------------------------------
__global__ __launch_bounds__(256) void flash_attn(
    const bf16* __restrict__ Q, const bf16* __restrict__ Kk,
    const bf16* __restrict__ V, bf16* __restrict__ O) {
  const int qt = (int)gridDim.x - 1 - (int)blockIdx.x;  // long blocks first
  const int h = blockIdx.y, b = blockIdx.z;
  const int t = threadIdx.x, w = t >> 6, l = t & 63;
  const int l15 = l & 15, quad = l >> 4;
  __shared__ __align__(16) bf16 Ks[2][64 * 64];    // [buf][key][d] swizzled
  __shared__ __align__(16) bf16 Vt[2][64 * 64];    // [buf][d][key] swizzled
  __shared__ __align__(16) bf16 Ps[4][16 * 64];    // per-wave P, swizzled

  const int qb = qt << 6;
  const int qrowA = qb + (w << 4) + l15;
  const bf16* qp = Q + (size_t)(b * S_ + qrowA) * D_ + h * HD_ + quad * 8;
  const s16x8 qf0 = *(const s16x8*)qp;
  const s16x8 qf1 = *(const s16x8*)(qp + 32);

  f32x4 o[4] = {};
  float m_i[4], l_i[4];
#pragma unroll
  for (int r = 0; r < 4; ++r) { m_i[r] = -1e30f; l_i[r] = 0.f; }

  // K staging: linear global_load_lds dest; source chunk pre-swizzled so
  // physical chunk = logical chunk ^ (row & 7)   (16B chunks, 8 per row).
  const int krow = t >> 3;                       // 0..31
  const int kchunk = (t & 7) ^ (krow & 7);       // pre-swizzled source chunk
  const bf16* Kg  = Kk + (size_t)(b * S_ + krow) * D_ + h * HD_ + (kchunk << 3);
  const bf16* Kg2 = Kg + (size_t)32 * D_;        // +32 rows: (row&7) unchanged
  const int vk = t & 63, vd = w << 4;
  const bf16* Vg = V + (size_t)(b * S_ + vk) * D_ + h * HD_ + vd;

  const int ntiles = qt + 1;
  const int swr = (l15 & 7) << 3;                // read-side xor (elements)

  // prologue: stage tile 0 into buffer 0
  {
    gl_lds16(Kg, Ks[0] + t * 8);
    gl_lds16(Kg2, Ks[0] + 2048 + t * 8);
    const s16x8 v0 = *(const s16x8*)(Vg);
    const s16x8 v1 = *(const s16x8*)(Vg + 8);
    short* vtp = (short*)Vt[0];
#pragma unroll
    for (int j = 0; j < 8; ++j) {
      const int d0 = vd + j, d1 = vd + 8 + j;
      vtp[d0 * 64 + (vk ^ ((d0 & 7) << 3))] = v0[j];
      vtp[d1 * 64 + (vk ^ ((d1 & 7) << 3))] = v1[j];
    }
  }

  for (int kt = 0; kt < ntiles; ++kt) {
    const int cur = kt & 1;
    __syncthreads();   // drains prev-iter gl_lds (vmcnt) + all waves' reads

    const bool pf = (kt + 1 < ntiles);
    s16x8 v0, v1;
    if (pf) {          // issue-early half of next-tile staging
      const size_t koff = (size_t)((kt + 1) << 6) * D_;
      gl_lds16(Kg + koff, Ks[cur ^ 1] + t * 8);
      gl_lds16(Kg2 + koff, Ks[cur ^ 1] + 2048 + t * 8);
      v0 = *(const s16x8*)(Vg + koff);
      v1 = *(const s16x8*)(Vg + koff + 8);
    }

    const bf16* Kc = Ks[cur];
    f32x4 sc[4];
#pragma unroll
    for (int ni = 0; ni < 4; ++ni) {
      const int r = ni * 16 + l15;
      const s16x8 kf0 = *(const s16x8*)&Kc[r * 64 + ((quad * 8) ^ swr)];
      const s16x8 kf1 = *(const s16x8*)&Kc[r * 64 + ((32 + quad * 8) ^ swr)];
      f32x4 z = {};
      z = mfma_bf16(qf0, kf0, z);
      sc[ni] = mfma_bf16(qf1, kf1, z);
    }

    float p[4][4];
#pragma unroll
    for (int ni = 0; ni < 4; ++ni) {
      const int key = (kt << 6) + ni * 16 + l15;
#pragma unroll
      for (int reg = 0; reg < 4; ++reg) {
        const int qrow = qb + (w << 4) + quad * 4 + reg;
        const float s = sc[ni][reg] * 0.125f;
        p[ni][reg] = (key > qrow) ? -1e30f : s;
      }
    }
#pragma unroll
    for (int reg = 0; reg < 4; ++reg) {
      float mx = fmaxf(fmaxf(p[0][reg], p[1][reg]), fmaxf(p[2][reg], p[3][reg]));
#pragma unroll
      for (int off = 1; off < 16; off <<= 1)
        mx = fmaxf(mx, __shfl_xor(mx, off, 64));
      const float mn = fmaxf(m_i[reg], mx);
      const float alpha = __expf(m_i[reg] - mn);
      m_i[reg] = mn;
      float sum = 0.f;
#pragma unroll
      for (int ni = 0; ni < 4; ++ni) {
        const float e = __expf(p[ni][reg] - mn);
        p[ni][reg] = e;
        sum += e;
      }
#pragma unroll
      for (int off = 1; off < 16; off <<= 1)
        sum += __shfl_xor(sum, off, 64);
      l_i[reg] = l_i[reg] * alpha + sum;
#pragma unroll
      for (int ni = 0; ni < 4; ++ni) o[ni][reg] *= alpha;
    }

    // P -> per-wave LDS (swizzled). No barrier needed: Ps[w] is private to
    // wave w; compiler orders the intra-wave ds_write -> ds_read.
#pragma unroll
    for (int reg = 0; reg < 4; ++reg)
#pragma unroll
      for (int ni = 0; ni < 4; ++ni) {
        const int row = quad * 4 + reg;
        Ps[w][row * 64 + ((ni * 16 + l15) ^ ((row & 7) << 3))] =
            __float2bfloat16(p[ni][reg]);
      }

    if (pf) {          // write-late half of V staging (T14)
      short* vtp = (short*)Vt[cur ^ 1];
#pragma unroll
      for (int j = 0; j < 8; ++j) {
        const int d0 = vd + j, d1 = vd + 8 + j;
        vtp[d0 * 64 + (vk ^ ((d0 & 7) << 3))] = v0[j];
        vtp[d1 * 64 + (vk ^ ((d1 & 7) << 3))] = v1[j];
      }
    }

    const bf16* Vc = Vt[cur];
#pragma unroll
    for (int ks = 0; ks < 2; ++ks) {
      const s16x8 pfr = *(const s16x8*)&Ps[w][l15 * 64 + ((ks * 32 + quad * 8) ^ swr)];
#pragma unroll
      for (int ni = 0; ni < 4; ++ni) {
        const int r = ni * 16 + l15;
        const s16x8 vf = *(const s16x8*)&Vc[r * 64 + ((ks * 32 + quad * 8) ^ swr)];
        o[ni] = mfma_bf16(pfr, vf, o[ni]);
      }
    }
  }

#pragma unroll
  for (int reg = 0; reg < 4; ++reg) {
    const float inv = 1.f / l_i[reg];
    const int row = b * S_ + qb + (w << 4) + quad * 4 + reg;
    bf16* op = O + (size_t)row * D_ + h * HD_ + l15;
#pragma unroll
    for (int ni = 0; ni < 4; ++ni)
      op[ni * 16] = __float2bfloat16(o[ni][reg] * inv);
  }
}

// ---------------------------------------------------------------------------
// LN1: h1 = LN(x_f32 + y1_bf16) -> bf16.   LN2: out = LN(sum_f32) -> fp32
// (in place). One block per 1024-col row.
// ---------------------------------------------------------------------------
template <int MODE>   // 0: LN1, 1: LN2
__global__ __launch_bounds__(256) void add_ln(
    const float* __restrict__ X, const bf16* __restrict__ Y,
    const float* __restrict__ g, const float* __restrict__ be,
    void* Out) {
  const int row = blockIdx.x, t = threadIdx.x;
  const size_t base = (size_t)row * D_ + t * 4;
  float v[4];
  float s = 0.f, q = 0.f;
#pragma unroll
  for (int i = 0; i < 4; ++i) {
    v[i] = X[base + i];
    if (MODE == 0) v[i] += b2f(*(const short*)&Y[base + i]);
    s += v[i];
    q += v[i] * v[i];
  }
#pragma unroll
  for (int off = 32; off; off >>= 1) {
    s += __shfl_down(s, off, 64);
    q += __shfl_down(q, off, 64);
  }
  __shared__ float rs[4], rq[4];
  const int w = t >> 6, l = t & 63;
  if (l == 0) { rs[w] = s; rq[w] = q; }
  __syncthreads();
  s = rs[0] + rs[1] + rs[2] + rs[3];
  q = rq[0] + rq[1] + rq[2] + rq[3];
  const float mu = s * (1.f / D_);
  const float var = q * (1.f / D_) - mu * mu;
  const float rstd = rsqrtf(var + 1e-5f);
#pragma unroll
  for (int i = 0; i < 4; ++i) {
    const float r = (v[i] - mu) * rstd * g[t * 4 + i] + be[t * 4 + i];
    if (MODE == 0) ((bf16*)Out)[base + i] = __float2bfloat16(r);
    else           ((float*)Out)[base + i] = r;
  }
}

extern "C" void kernel_launch(void* const* d_in, const int* in_sizes, int n_in,
                              void* d_out, int out_size, void* d_ws, size_t ws_size,
                              hipStream_t stream) {
  const float* x     = (const float*)d_in[0];
  const float* qkv_b = (const float*)d_in[2];
  const float* out_b = (const float*)d_in[4];
  const float* b1    = (const float*)d_in[6];
  const float* b2    = (const float*)d_in[8];
  const float* l1w   = (const float*)d_in[9];
  const float* l1b   = (const float*)d_in[10];
  const float* l2w   = (const float*)d_in[11];
  const float* l2b   = (const float*)d_in[12];

  float* out    = (float*)d_out;
  float* kcache = out + (size_t)M_ * D_;
  float* vcache = kcache + (size_t)M_ * D_;

  // ws (bf16 elems). High-water 28M elems = 56 MB (<75 MB established safe).
  //  [0,4M)   xc      -> attnb (after QKV)
  //  [4,7M)   wqkv    -> h1 (after out-proj; h1 spans [4,8M))
  //  [7,8M)   wout
  //  [8,12M)  w1c
  //  [12,16M) w2c
  //  [16,20M) qbuf    -> y1 (after flash)
  //  [20,24M) kb      -> ffb chunk (after flash; ffb spans [20,28M))
  //  [24,28M) vb
  bf16* ws    = (bf16*)d_ws;
  bf16* xc    = ws;
  bf16* attnb = ws;
  bf16* wqkv  = ws + 4 * MEG;
  bf16* h1    = ws + 4 * MEG;
  bf16* wout  = ws + 7 * MEG;
  bf16* w1c   = ws + 8 * MEG;
  bf16* w2c   = ws + 12 * MEG;
  bf16* qbuf  = ws + 16 * MEG;
  bf16* y1    = ws + 16 * MEG;
  bf16* kb    = ws + 20 * MEG;
  bf16* ffb   = ws + 20 * MEG;
  bf16* vb    = ws + 24 * MEG;

  const dim3 blk(256);
  auto cvt = [&](const void* src, bf16* dst, int n) {
    cvt_f2b<<<dim3((n + 2047) / 2048), blk, 0, stream>>>((const float*)src, dst, n);
  };
  cvt(d_in[0], xc,   M_ * D_);
  cvt(d_in[1], wqkv, 3 * D_ * D_);
  cvt(d_in[3], wout, D_ * D_);
  cvt(d_in[5], w1c,  FFD_ * D_);
  cvt(d_in[7], w2c,  D_ * FFD_);

  // QKV: q->qbuf bf16; k/v->fp32 caches + bf16 ws copies.
  gemm_bt<3><<<dim3(3 * D_ / 128, M_ / 128), blk, 0, stream>>>(
      xc, wqkv, qkv_b, qbuf, nullptr, kcache, kb, vcache, vb, nullptr,
      M_, 3 * D_, D_);
  flash_attn<<<dim3(S_ / 64, H_, B_), blk, 0, stream>>>(qbuf, kb, vb, attnb);
  // out-proj -> y1 bf16 (overwrites dead qbuf)
  gemm_bt<0><<<dim3(D_ / 128, M_ / 128), blk, 0, stream>>>(
      attnb, wout, out_b, y1, nullptr, nullptr, nullptr, nullptr, nullptr,
      nullptr, M_, D_, D_);
  // h1 = LN(x + y1) -> bf16 (overwrites dead wqkv)
  add_ln<0><<<dim3(M_), blk, 0, stream>>>(x, y1, l1w, l1b, h1);
  // MLP, 2 chunks of 2048 rows; ffb reuses kb/vb region; sum -> d_out fp32.
  for (int c = 0; c < 2; ++c) {
    const bf16* hrows = h1 + (size_t)c * 2048 * D_;
    float* srows = out + (size_t)c * 2048 * D_;
    gemm_bt<1><<<dim3(FFD_ / 128, 2048 / 128), blk, 0, stream>>>(
        hrows, w1c, b1, ffb, nullptr, nullptr, nullptr, nullptr, nullptr,
        nullptr, 2048, FFD_, D_);
    gemm_bt<2><<<dim3(D_ / 128, 2048 / 128), blk, 0, stream>>>(
        ffb, w2c, b2, nullptr, srows, nullptr, nullptr, nullptr, nullptr,
        hrows, 2048, D_, FFD_);
  }
  // out = LN(sum) in place, fp32.
  add_ln<1><<<dim3(M_), blk, 0, stream>>>(out, nullptr, l2w, l2b, out);
}

// Round 2
// 566.241 us; speedup vs baseline: 1.0939x; 1.0787x over previous
//
#include <hip/hip_runtime.h>
#include <hip/hip_bf16.h>
#include <stdint.h>

typedef __hip_bfloat16 bf16;
typedef __attribute__((ext_vector_type(8))) short s16x8;
typedef __attribute__((ext_vector_type(4))) float f32x4;

#define B_   2
#define S_   2048
#define D_   1024
#define H_   16
#define HD_  64
#define FFD_ 4096
#define M_   4096
#define MEG  ((size_t)1048576)

__device__ __forceinline__ f32x4 mfma_bf16(s16x8 a, s16x8 b, f32x4 c) {
  return __builtin_amdgcn_mfma_f32_16x16x32_bf16(a, b, c, 0, 0, 0);
}

__device__ __forceinline__ void gl_lds16(const bf16* g, bf16* l) {
  __builtin_amdgcn_global_load_lds(
      (const __attribute__((address_space(1))) void*)g,
      (__attribute__((address_space(3))) void*)l, 16, 0, 0);
}

__device__ __forceinline__ float b2f(short u) {
  union { uint32_t i; float f; } z;
  z.i = ((uint32_t)(unsigned short)u) << 16;
  return z.f;
}
__device__ __forceinline__ short f2b(float f) {
  const bf16 h = __float2bfloat16(f);
  return *(const short*)&h;
}

// ---------------------------------------------------------------------------
// fp32 -> bf16 conversion (inputs are fp32; GEMM operands need bf16).
// ---------------------------------------------------------------------------
__global__ __launch_bounds__(256) void cvt_f2b(
    const float* __restrict__ src, bf16* __restrict__ dst, int n) {
  const int idx = (blockIdx.x * 256 + threadIdx.x) * 8;
  if (idx >= n) return;
  s16x8 o;
#pragma unroll
  for (int i = 0; i < 8; ++i) o[i] = f2b(src[idx + i]);
  *(s16x8*)(dst + idx) = o;
}

// ---------------------------------------------------------------------------
// MFMA NT GEMM: C[m,n] = sum_k A[m,k]*W[n,k] + bias[n]  (bias fp32)
// 128x128 tile, BK=32, 4 waves (2x2), 4x4 16x16x32 frags.
// MODE 0: C -> bf16 Cb             (out-proj -> y1)
// MODE 1: relu, C -> bf16 Cb       (MLP1 -> ff)
// MODE 2: C + resid(bf16) -> fp32 Cf  (MLP2 -> sum in d_out)
// MODE 3: QKV split: seg0 q*0.125 -> bf16 Cb (pre-scaled for attn, 2^-3
//         exact in bf16); seg1 k->fp32 Kf + bf16 Kb; seg2 v->fp32 Vf+bf16 Vb.
// ---------------------------------------------------------------------------
template <int MODE>
__global__ __launch_bounds__(256) void gemm_bt(
    const bf16* __restrict__ A, const bf16* __restrict__ W,
    const float* __restrict__ bias,
    bf16* __restrict__ Cb, float* __restrict__ Cf,
    float* __restrict__ Kf, bf16* __restrict__ Kb,
    float* __restrict__ Vf, bf16* __restrict__ Vb,
    const bf16* __restrict__ Res,
    int M, int N, int K) {
  __shared__ __align__(16) bf16 As[128 * 32];
  __shared__ __align__(16) bf16 Bs[128 * 32];
  const int t = threadIdx.x;
  const int m0 = blockIdx.y << 7, n0 = blockIdx.x << 7;
  const int w = t >> 6, l = t & 63;
  const int wm = (w >> 1) << 6, wn = (w & 1) << 6;
  const int l15 = l & 15, quad = l >> 4;

  f32x4 acc[4][4] = {};

  const int srow = t >> 2;          // 0..63
  const int scol = (t & 3) << 3;    // 0,8,16,24
  const bf16* Ag  = A + (size_t)(m0 + srow) * K + scol;
  const bf16* Ag2 = Ag + ((size_t)K << 6);   // +64 rows
  const bf16* Wg  = W + (size_t)(n0 + srow) * K + scol;
  const bf16* Wg2 = Wg + ((size_t)K << 6);
  bf16* Al  = As + t * 8;
  bf16* Al2 = Al + 2048;
  bf16* Bl  = Bs + t * 8;
  bf16* Bl2 = Bl + 2048;

  for (int k0 = 0; k0 < K; k0 += 32) {
    __syncthreads();
    gl_lds16(Ag + k0, Al);
    gl_lds16(Ag2 + k0, Al2);
    gl_lds16(Wg + k0, Bl);
    gl_lds16(Wg2 + k0, Bl2);
    __syncthreads();
    const s16x8* As8 = (const s16x8*)As;
    const s16x8* Bs8 = (const s16x8*)Bs;
    s16x8 af[4], bfr[4];
#pragma unroll
    for (int i = 0; i < 4; ++i) af[i]  = As8[((wm + i * 16 + l15) << 2) + quad];
#pragma unroll
    for (int i = 0; i < 4; ++i) bfr[i] = Bs8[((wn + i * 16 + l15) << 2) + quad];
#pragma unroll
    for (int mi = 0; mi < 4; ++mi)
#pragma unroll
      for (int ni = 0; ni < 4; ++ni)
        acc[mi][ni] = mfma_bf16(af[mi], bfr[ni], acc[mi][ni]);
  }

  float bv[4];
#pragma unroll
  for (int ni = 0; ni < 4; ++ni)
    bv[ni] = bias[n0 + wn + ni * 16 + l15];

  const int seg = n0 >> 10, nb = n0 & 1023;
#pragma unroll
  for (int mi = 0; mi < 4; ++mi) {
#pragma unroll
    for (int reg = 0; reg < 4; ++reg) {
      const int row = m0 + wm + mi * 16 + quad * 4 + reg;
#pragma unroll
      for (int ni = 0; ni < 4; ++ni) {
        float v = acc[mi][ni][reg] + bv[ni];
        if (MODE == 0) {
          Cb[(size_t)row * N + n0 + wn + ni * 16 + l15] = __float2bfloat16(v);
        } else if (MODE == 1) {
          v = fmaxf(v, 0.f);
          Cb[(size_t)row * N + n0 + wn + ni * 16 + l15] = __float2bfloat16(v);
        } else if (MODE == 2) {
          const size_t o = (size_t)row * N + n0 + wn + ni * 16 + l15;
          Cf[o] = v + b2f(*(const short*)&Res[o]);
        } else {  // MODE 3
          const size_t o = (size_t)row * 1024 + nb + wn + ni * 16 + l15;
          if (seg == 0) {
            Cb[o] = __float2bfloat16(v * 0.125f);   // pre-scale Q by 1/sqrt(hd)
          } else if (seg == 1) {
            Kf[o] = v; Kb[o] = __float2bfloat16(v);
          } else {
            Vf[o] = v; Vb[o] = __float2bfloat16(v);
          }
        }
      }
    }
  }
}

// ---------------------------------------------------------------------------
// MFMA flash attention, causal, hd=64. Block = (64 q-rows, head, batch).
// Q is PRE-SCALED by 0.125 (done in QKV GEMM epilogue).
// v3: 2-deep score pipeline: QK(kt) MFMA overlaps softmax(kt-1)+PV(kt-1)
//     (independent regs, no barrier between). K double-buffered via
//     global_load_lds (source pre-swizzled); V double-buffered via
//     reg-staged swizzled writes (issue-early / write-late).
//     Softmax chain cuts: per-lane partial l (one reduce at end),
//     diag-only masking, defer-max (THR=8, wave-uniform skip).
// ---------------------------------------------------------------------------
__global__ __launch_bounds__(256, 4) void flash_attn(
    const bf16* __restrict__ Q, const bf16* __restrict__ Kk,
    const bf16* __restrict__ V, bf16* __restrict__ O) {
  const int qt = (int)gridDim.x - 1 - (int)blockIdx.x;  // long blocks first
  const int h = blockIdx.y, b = blockIdx.z;
  const int t = threadIdx.x, w = t >> 6, l = t & 63;
  const int l15 = l & 15, quad = l >> 4;
  __shared__ __align__(16) bf16 Ks[2][64 * 64];    // [buf][key][d] swizzled
  __shared__ __align__(16) bf16 Vt[2][64 * 64];    // [buf][d][key] swizzled
  __shared__ __align__(16) bf16 Ps[4][16 * 64];    // per-wave P, swizzled

  const int qb = qt << 6;
  const bf16* qp = Q + (size_t)(b * S_ + qb + (w << 4) + l15) * D_ + h * HD_ + quad * 8;
  const s16x8 qf0 = *(const s16x8*)qp;
  const s16x8 qf1 = *(const s16x8*)(qp + 32);

  f32x4 o[4] = {};
  float m_i[4], l_p[4];
#pragma unroll
  for (int r = 0; r < 4; ++r) { m_i[r] = -1e30f; l_p[r] = 0.f; }

  // K staging: linear global_load_lds dest; source chunk pre-swizzled.
  const int krow = t >> 3;                       // 0..31
  const int kchunk = (t & 7) ^ (krow & 7);
  const bf16* Kg  = Kk + (size_t)(b * S_ + krow) * D_ + h * HD_ + (kchunk << 3);
  const bf16* Kg2 = Kg + (size_t)32 * D_;
  const int vk = t & 63, vd = w << 4;
  const bf16* Vg = V + (size_t)(b * S_ + vk) * D_ + h * HD_ + vd;

  const int nt = qt + 1;
  const int swr = (l15 & 7) << 3;                // read-side xor (elements)

  s16x8 vr0, vr1;                                // V staging regs (1 tile)
  f32x4 scP[4], scN[4];                          // 2-deep score pipeline

  auto issueK = [&](int kt2) {
    bf16* dst = Ks[kt2 & 1] + t * 8;
    const size_t koff = (size_t)(kt2 << 6) * D_;
    gl_lds16(Kg + koff, dst);
    gl_lds16(Kg2 + koff, dst + 2048);
  };
  auto loadV = [&](int kt2) {
    const size_t koff = (size_t)(kt2 << 6) * D_;
    vr0 = *(const s16x8*)(Vg + koff);
    vr1 = *(const s16x8*)(Vg + koff + 8);
  };
  auto writeV = [&](int kt2) {
    short* vtp = (short*)Vt[kt2 & 1];
#pragma unroll
    for (int j = 0; j < 8; ++j) {
      const int d0 = vd + j, d1 = vd + 8 + j;
      vtp[d0 * 64 + (vk ^ ((d0 & 7) << 3))] = vr0[j];
      vtp[d1 * 64 + (vk ^ ((d1 & 7) << 3))] = vr1[j];
    }
  };
  auto qk = [&](int kt2, f32x4 (&sc)[4]) {
    const bf16* Kc = Ks[kt2 & 1];
#pragma unroll
    for (int ni = 0; ni < 4; ++ni) {
      const int r = ni * 16 + l15;
      const s16x8 kf0 = *(const s16x8*)&Kc[r * 64 + ((quad * 8) ^ swr)];
      const s16x8 kf1 = *(const s16x8*)&Kc[r * 64 + ((32 + quad * 8) ^ swr)];
      f32x4 z = {};
      z = mfma_bf16(qf0, kf0, z);
      sc[ni] = mfma_bf16(qf1, kf1, z);
    }
  };
  auto smax_pv = [&](int j, f32x4 (&sc)[4]) {
    if (j == nt - 1) {          // only the diagonal tile needs masking
#pragma unroll
      for (int ni = 0; ni < 4; ++ni) {
        const int key = (j << 6) + ni * 16 + l15;
#pragma unroll
        for (int reg = 0; reg < 4; ++reg) {
          const int qrow = qb + (w << 4) + quad * 4 + reg;
          if (key > qrow) sc[ni][reg] = -1e30f;
        }
      }
    }
    float mx[4];
#pragma unroll
    for (int reg = 0; reg < 4; ++reg)
      mx[reg] = fmaxf(fmaxf(sc[0][reg], sc[1][reg]),
                      fmaxf(sc[2][reg], sc[3][reg]));
#pragma unroll
    for (int off = 1; off < 16; off <<= 1)
#pragma unroll
      for (int reg = 0; reg < 4; ++reg)
        mx[reg] = fmaxf(mx[reg], __shfl_xor(mx[reg], off, 64));
    // defer-max (T13): rescale only if some row's max grew past THR=8
    bool up = false;
#pragma unroll
    for (int reg = 0; reg < 4; ++reg) up = up || (mx[reg] > m_i[reg] + 8.f);
    if (__any(up)) {
#pragma unroll
      for (int reg = 0; reg < 4; ++reg) {
        const float nm = fmaxf(m_i[reg], mx[reg]);
        const float al = __expf(m_i[reg] - nm);
        m_i[reg] = nm;
        l_p[reg] *= al;
#pragma unroll
        for (int ni = 0; ni < 4; ++ni) o[ni][reg] *= al;
      }
    }
#pragma unroll
    for (int reg = 0; reg < 4; ++reg) {
      float s = 0.f;
#pragma unroll
      for (int ni = 0; ni < 4; ++ni) {
        const float e = __expf(sc[ni][reg] - m_i[reg]);
        sc[ni][reg] = e;
        s += e;
      }
      l_p[reg] += s;              // per-lane partial; reduced once at end
    }
#pragma unroll
    for (int reg = 0; reg < 4; ++reg)
#pragma unroll
      for (int ni = 0; ni < 4; ++ni) {
        const int row = quad * 4 + reg;
        Ps[w][row * 64 + ((ni * 16 + l15) ^ ((row & 7) << 3))] =
            __float2bfloat16(sc[ni][reg]);
      }
    const bf16* Vc = Vt[j & 1];
#pragma unroll
    for (int ks = 0; ks < 2; ++ks) {
      const s16x8 pfr =
          *(const s16x8*)&Ps[w][l15 * 64 + ((ks * 32 + quad * 8) ^ swr)];
#pragma unroll
      for (int ni = 0; ni < 4; ++ni) {
        const int r = ni * 16 + l15;
        const s16x8 vf = *(const s16x8*)&Vc[r * 64 + ((ks * 32 + quad * 8) ^ swr)];
        o[ni] = mfma_bf16(pfr, vf, o[ni]);
      }
    }
  };

  // ---- prologue ----
  issueK(0);
  loadV(0);
  __syncthreads();                 // K(0) in LDS, V(0) in regs
  writeV(0);                       // Vt[0] = V(0), published by next barrier
  if (nt > 1) { issueK(1); }
  qk(0, scP);
  if (nt > 1) { loadV(1); writeV(1); }   // Vt[1] = V(1) (vmcnt dep auto)

  // ---- main loop: iter kt computes QK(kt) while finishing tile kt-1 ----
  auto body = [&](int kt2, f32x4 (&sOld)[4], f32x4 (&sNew)[4]) {
    __syncthreads();               // publishes Ks[kt2&1], Vt writes
    const bool pf = (kt2 + 1 < nt);
    if (pf) { issueK(kt2 + 1); loadV(kt2 + 1); }
    qk(kt2, sNew);                 // MFMA — independent of sOld softmax
    smax_pv(kt2 - 1, sOld);        // VALU + PV MFMA on tile kt2-1
    if (pf) {
      __syncthreads();             // all waves done reading Vt[(kt2-1)&1]
      writeV(kt2 + 1);             // overwrite that buffer with V(kt2+1)
    }
  };

  int kt = 1;
  for (; kt + 1 < nt; kt += 2) {
    body(kt, scP, scN);
    body(kt + 1, scN, scP);
  }
  if (kt < nt) body(kt, scP, scN);

  // ---- epilogue: finish last tile ----
  if ((nt - 1) & 1) smax_pv(nt - 1, scN);
  else              smax_pv(nt - 1, scP);

  // deferred l reduction (once, not per tile)
  float inv[4];
#pragma unroll
  for (int off = 1; off < 16; off <<= 1)
#pragma unroll
    for (int reg = 0; reg < 4; ++reg)
      l_p[reg] += __shfl_xor(l_p[reg], off, 64);
#pragma unroll
  for (int reg = 0; reg < 4; ++reg) inv[reg] = 1.f / l_p[reg];

#pragma unroll
  for (int reg = 0; reg < 4; ++reg) {
    const int row = b * S_ + qb + (w << 4) + quad * 4 + reg;
    bf16* op = O + (size_t)row * D_ + h * HD_ + l15;
#pragma unroll
    for (int ni = 0; ni < 4; ++ni)
      op[ni * 16] = __float2bfloat16(o[ni][reg] * inv[reg]);
  }
}

// ---------------------------------------------------------------------------
// LN1: h1 = LN(x_f32 + y1_bf16) -> bf16.   LN2: out = LN(sum_f32) -> fp32
// (in place). One block per 1024-col row.
// ---------------------------------------------------------------------------
template <int MODE>   // 0: LN1, 1: LN2
__global__ __launch_bounds__(256) void add_ln(
    const float* __restrict__ X, const bf16* __restrict__ Y,
    const float* __restrict__ g, const float* __restrict__ be,
    void* Out) {
  const int row = blockIdx.x, t = threadIdx.x;
  const size_t base = (size_t)row * D_ + t * 4;
  float v[4];
  float s = 0.f, q = 0.f;
#pragma unroll
  for (int i = 0; i < 4; ++i) {
    v[i] = X[base + i];
    if (MODE == 0) v[i] += b2f(*(const short*)&Y[base + i]);
    s += v[i];
    q += v[i] * v[i];
  }
#pragma unroll
  for (int off = 32; off; off >>= 1) {
    s += __shfl_down(s, off, 64);
    q += __shfl_down(q, off, 64);
  }
  __shared__ float rs[4], rq[4];
  const int w = t >> 6, l = t & 63;
  if (l == 0) { rs[w] = s; rq[w] = q; }
  __syncthreads();
  s = rs[0] + rs[1] + rs[2] + rs[3];
  q = rq[0] + rq[1] + rq[2] + rq[3];
  const float mu = s * (1.f / D_);
  const float var = q * (1.f / D_) - mu * mu;
  const float rstd = rsqrtf(var + 1e-5f);
#pragma unroll
  for (int i = 0; i < 4; ++i) {
    const float r = (v[i] - mu) * rstd * g[t * 4 + i] + be[t * 4 + i];
    if (MODE == 0) ((bf16*)Out)[base + i] = __float2bfloat16(r);
    else           ((float*)Out)[base + i] = r;
  }
}

extern "C" void kernel_launch(void* const* d_in, const int* in_sizes, int n_in,
                              void* d_out, int out_size, void* d_ws, size_t ws_size,
                              hipStream_t stream) {
  const float* x     = (const float*)d_in[0];
  const float* qkv_b = (const float*)d_in[2];
  const float* out_b = (const float*)d_in[4];
  const float* b1    = (const float*)d_in[6];
  const float* b2    = (const float*)d_in[8];
  const float* l1w   = (const float*)d_in[9];
  const float* l1b   = (const float*)d_in[10];
  const float* l2w   = (const float*)d_in[11];
  const float* l2b   = (const float*)d_in[12];

  float* out    = (float*)d_out;
  float* kcache = out + (size_t)M_ * D_;
  float* vcache = kcache + (size_t)M_ * D_;

  // ws (bf16 elems). High-water 28M elems = 56 MB (<75 MB established safe).
  //  [0,4M)   xc      -> attnb (after QKV)
  //  [4,7M)   wqkv    -> h1 (after out-proj; h1 spans [4,8M))
  //  [7,8M)   wout
  //  [8,12M)  w1c
  //  [12,16M) w2c
  //  [16,20M) qbuf    -> y1 (after flash)
  //  [20,24M) kb      -> ffb chunk (after flash; ffb spans [20,28M))
  //  [24,28M) vb
  bf16* ws    = (bf16*)d_ws;
  bf16* xc    = ws;
  bf16* attnb = ws;
  bf16* wqkv  = ws + 4 * MEG;
  bf16* h1    = ws + 4 * MEG;
  bf16* wout  = ws + 7 * MEG;
  bf16* w1c   = ws + 8 * MEG;
  bf16* w2c   = ws + 12 * MEG;
  bf16* qbuf  = ws + 16 * MEG;
  bf16* y1    = ws + 16 * MEG;
  bf16* kb    = ws + 20 * MEG;
  bf16* ffb   = ws + 20 * MEG;
  bf16* vb    = ws + 24 * MEG;

  const dim3 blk(256);
  auto cvt = [&](const void* src, bf16* dst, int n) {
    cvt_f2b<<<dim3((n + 2047) / 2048), blk, 0, stream>>>((const float*)src, dst, n);
  };
  cvt(d_in[0], xc,   M_ * D_);
  cvt(d_in[1], wqkv, 3 * D_ * D_);
  cvt(d_in[3], wout, D_ * D_);
  cvt(d_in[5], w1c,  FFD_ * D_);
  cvt(d_in[7], w2c,  D_ * FFD_);

  // QKV: q (pre-scaled 0.125) -> qbuf bf16; k/v->fp32 caches + bf16 ws copies.
  gemm_bt<3><<<dim3(3 * D_ / 128, M_ / 128), blk, 0, stream>>>(
      xc, wqkv, qkv_b, qbuf, nullptr, kcache, kb, vcache, vb, nullptr,
      M_, 3 * D_, D_);
  flash_attn<<<dim3(S_ / 64, H_, B_), blk, 0, stream>>>(qbuf, kb, vb, attnb);
  // out-proj -> y1 bf16 (overwrites dead qbuf)
  gemm_bt<0><<<dim3(D_ / 128, M_ / 128), blk, 0, stream>>>(
      attnb, wout, out_b, y1, nullptr, nullptr, nullptr, nullptr, nullptr,
      nullptr, M_, D_, D_);
  // h1 = LN(x + y1) -> bf16 (overwrites dead wqkv)
  add_ln<0><<<dim3(M_), blk, 0, stream>>>(x, y1, l1w, l1b, h1);
  // MLP, 2 chunks of 2048 rows; ffb reuses kb/vb region; sum -> d_out fp32.
  for (int c = 0; c < 2; ++c) {
    const bf16* hrows = h1 + (size_t)c * 2048 * D_;
    float* srows = out + (size_t)c * 2048 * D_;
    gemm_bt<1><<<dim3(FFD_ / 128, 2048 / 128), blk, 0, stream>>>(
        hrows, w1c, b1, ffb, nullptr, nullptr, nullptr, nullptr, nullptr,
        nullptr, 2048, FFD_, D_);
    gemm_bt<2><<<dim3(D_ / 128, 2048 / 128), blk, 0, stream>>>(
        ffb, w2c, b2, nullptr, srows, nullptr, nullptr, nullptr, nullptr,
        hrows, 2048, D_, FFD_);
  }
  // out = LN(sum) in place, fp32.
  add_ln<1><<<dim3(M_), blk, 0, stream>>>(out, nullptr, l2w, l2b, out);
}

// Round 3
// 518.928 us; speedup vs baseline: 1.1936x; 1.0912x over previous
//
#include <hip/hip_runtime.h>
#include <hip/hip_bf16.h>
#include <stdint.h>

typedef __hip_bfloat16 bf16;
typedef __attribute__((ext_vector_type(8))) short s16x8;
typedef __attribute__((ext_vector_type(4))) float f32x4;

#define B_   2
#define S_   2048
#define D_   1024
#define H_   16
#define HD_  64
#define FFD_ 4096
#define M_   4096
#define MEG  ((size_t)1048576)

__device__ __forceinline__ f32x4 mfma_bf16(s16x8 a, s16x8 b, f32x4 c) {
  return __builtin_amdgcn_mfma_f32_16x16x32_bf16(a, b, c, 0, 0, 0);
}

__device__ __forceinline__ void gl_lds16(const bf16* g, bf16* l) {
  __builtin_amdgcn_global_load_lds(
      (const __attribute__((address_space(1))) void*)g,
      (__attribute__((address_space(3))) void*)l, 16, 0, 0);
}

__device__ __forceinline__ float b2f(short u) {
  union { uint32_t i; float f; } z;
  z.i = ((uint32_t)(unsigned short)u) << 16;
  return z.f;
}
__device__ __forceinline__ short f2b(float f) {
  const bf16 h = __float2bfloat16(f);
  return *(const short*)&h;
}

// ---------------------------------------------------------------------------
// fp32 -> bf16 conversion (inputs are fp32; GEMM operands need bf16).
// ---------------------------------------------------------------------------
__global__ __launch_bounds__(256) void cvt_f2b(
    const float* __restrict__ src, bf16* __restrict__ dst, int n) {
  const int idx = (blockIdx.x * 256 + threadIdx.x) * 8;
  if (idx >= n) return;
  s16x8 o;
#pragma unroll
  for (int i = 0; i < 8; ++i) o[i] = f2b(src[idx + i]);
  *(s16x8*)(dst + idx) = o;
}

// ---------------------------------------------------------------------------
// MFMA NT GEMM: C[m,n] = sum_k A[m,k]*W[n,k] + bias[n]  (bias fp32)
// 128x128 tile, BK=32, 4 waves (2x2), 4x4 16x16x32 frags.
// MODE 0: C -> bf16 Cb             (out-proj -> y1)
// MODE 1: relu, C -> bf16 Cb       (MLP1 -> ff)
// MODE 2: C + resid(bf16) -> fp32 Cf  (MLP2 -> sum in d_out)
// MODE 3: QKV split: seg0 q*0.125 -> bf16 Cb (pre-scaled for attn);
//         seg1 k->fp32 Kf + bf16 Kb; seg2 v->fp32 Vf + bf16 Vb.
// ---------------------------------------------------------------------------
template <int MODE>
__global__ __launch_bounds__(256) void gemm_bt(
    const bf16* __restrict__ A, const bf16* __restrict__ W,
    const float* __restrict__ bias,
    bf16* __restrict__ Cb, float* __restrict__ Cf,
    float* __restrict__ Kf, bf16* __restrict__ Kb,
    float* __restrict__ Vf, bf16* __restrict__ Vb,
    const bf16* __restrict__ Res,
    int M, int N, int K) {
  __shared__ __align__(16) bf16 As[128 * 32];
  __shared__ __align__(16) bf16 Bs[128 * 32];
  const int t = threadIdx.x;
  const int m0 = blockIdx.y << 7, n0 = blockIdx.x << 7;
  const int w = t >> 6, l = t & 63;
  const int wm = (w >> 1) << 6, wn = (w & 1) << 6;
  const int l15 = l & 15, quad = l >> 4;

  f32x4 acc[4][4] = {};

  const int srow = t >> 2;          // 0..63
  const int scol = (t & 3) << 3;    // 0,8,16,24
  const bf16* Ag  = A + (size_t)(m0 + srow) * K + scol;
  const bf16* Ag2 = Ag + ((size_t)K << 6);   // +64 rows
  const bf16* Wg  = W + (size_t)(n0 + srow) * K + scol;
  const bf16* Wg2 = Wg + ((size_t)K << 6);
  bf16* Al  = As + t * 8;
  bf16* Al2 = Al + 2048;
  bf16* Bl  = Bs + t * 8;
  bf16* Bl2 = Bl + 2048;

  for (int k0 = 0; k0 < K; k0 += 32) {
    __syncthreads();
    gl_lds16(Ag + k0, Al);
    gl_lds16(Ag2 + k0, Al2);
    gl_lds16(Wg + k0, Bl);
    gl_lds16(Wg2 + k0, Bl2);
    __syncthreads();
    const s16x8* As8 = (const s16x8*)As;
    const s16x8* Bs8 = (const s16x8*)Bs;
    s16x8 af[4], bfr[4];
#pragma unroll
    for (int i = 0; i < 4; ++i) af[i]  = As8[((wm + i * 16 + l15) << 2) + quad];
#pragma unroll
    for (int i = 0; i < 4; ++i) bfr[i] = Bs8[((wn + i * 16 + l15) << 2) + quad];
#pragma unroll
    for (int mi = 0; mi < 4; ++mi)
#pragma unroll
      for (int ni = 0; ni < 4; ++ni)
        acc[mi][ni] = mfma_bf16(af[mi], bfr[ni], acc[mi][ni]);
  }

  float bv[4];
#pragma unroll
  for (int ni = 0; ni < 4; ++ni)
    bv[ni] = bias[n0 + wn + ni * 16 + l15];

  const int seg = n0 >> 10, nb = n0 & 1023;
#pragma unroll
  for (int mi = 0; mi < 4; ++mi) {
#pragma unroll
    for (int reg = 0; reg < 4; ++reg) {
      const int row = m0 + wm + mi * 16 + quad * 4 + reg;
#pragma unroll
      for (int ni = 0; ni < 4; ++ni) {
        float v = acc[mi][ni][reg] + bv[ni];
        if (MODE == 0) {
          Cb[(size_t)row * N + n0 + wn + ni * 16 + l15] = __float2bfloat16(v);
        } else if (MODE == 1) {
          v = fmaxf(v, 0.f);
          Cb[(size_t)row * N + n0 + wn + ni * 16 + l15] = __float2bfloat16(v);
        } else if (MODE == 2) {
          const size_t o = (size_t)row * N + n0 + wn + ni * 16 + l15;
          Cf[o] = v + b2f(*(const short*)&Res[o]);
        } else {  // MODE 3
          const size_t o = (size_t)row * 1024 + nb + wn + ni * 16 + l15;
          if (seg == 0) {
            Cb[o] = __float2bfloat16(v * 0.125f);   // pre-scale Q by 1/sqrt(hd)
          } else if (seg == 1) {
            Kf[o] = v; Kb[o] = __float2bfloat16(v);
          } else {
            Vf[o] = v; Vb[o] = __float2bfloat16(v);
          }
        }
      }
    }
  }
}

// ---------------------------------------------------------------------------
// MFMA flash attention v4, causal, hd=64.
// Block = (q-tile PAIR {bxp, 31-bxp}, head, batch): every block does exactly
// 33 k-tiles -> perfect inter-CU balance (fixes the 124-vs-66-tile worst-CU
// skew that bounded v3). Grid 16x16x2 = 512 blocks, 2/CU.
// K and V both reg-staged (global->reg->swizzled ds_write): no global_load_lds
// => no vmcnt drain at barriers. Both per-tile barriers are raw s_barrier +
// lgkmcnt(0) only (T4); the only vmem waits are compiler-counted at WRITEKV,
// one full iteration after issue.
// Macro-expanded pipeline with NAMED score regs (sA0..sB3) — no lambdas, no
// reference-array params => no scratch (v3 spilled ~20 MB, WRITE_SIZE 27.7MB).
// Swizzle: elem col ^= (row&7)<<3 on Ks/Vt/Ps (bank-conflict-free, rounds 1-2).
// ---------------------------------------------------------------------------
#define BAR_SYNC() do {                                                      \
    asm volatile("s_waitcnt lgkmcnt(0)" ::: "memory");                       \
    __builtin_amdgcn_s_barrier();                                            \
    __builtin_amdgcn_sched_barrier(0);                                       \
  } while (0)

#define ISSUE(KT) do { const size_t ko_ = (size_t)((KT) << 6) * D_;          \
    kr0 = *(const s16x8*)(Kg + ko_);                                         \
    kr1 = *(const s16x8*)(Kg2 + ko_);                                        \
    vr0 = *(const s16x8*)(Vg + ko_);                                         \
    vr1 = *(const s16x8*)(Vg + ko_ + 8);                                     \
  } while (0)

#define WRITEKV(KT) do {                                                     \
    bf16* kd_ = Ks[(KT) & 1];                                                \
    *(s16x8*)&kd_[krow * 64 + (kchunk << 3)] = kr0;                          \
    *(s16x8*)&kd_[(krow + 32) * 64 + (kchunk << 3)] = kr1;                   \
    short* vp_ = (short*)Vt[(KT) & 1];                                       \
    _Pragma("unroll") for (int j = 0; j < 8; ++j) {                          \
      const int d0_ = vd + j, d1_ = vd + 8 + j;                              \
      vp_[d0_ * 64 + (vk ^ ((d0_ & 7) << 3))] = vr0[j];                      \
      vp_[d1_ * 64 + (vk ^ ((d1_ & 7) << 3))] = vr1[j];                      \
    }                                                                        \
  } while (0)

#define QK_LOAD(KT) do { const bf16* Kq_ = Ks[(KT) & 1];                     \
    ka0 = *(const s16x8*)&Kq_[( 0 + l15) * 64 + (( 0 + quad * 8) ^ swr)];    \
    ka1 = *(const s16x8*)&Kq_[(16 + l15) * 64 + (( 0 + quad * 8) ^ swr)];    \
    ka2 = *(const s16x8*)&Kq_[(32 + l15) * 64 + (( 0 + quad * 8) ^ swr)];    \
    ka3 = *(const s16x8*)&Kq_[(48 + l15) * 64 + (( 0 + quad * 8) ^ swr)];    \
    kb0 = *(const s16x8*)&Kq_[( 0 + l15) * 64 + ((32 + quad * 8) ^ swr)];    \
    kb1 = *(const s16x8*)&Kq_[(16 + l15) * 64 + ((32 + quad * 8) ^ swr)];    \
    kb2 = *(const s16x8*)&Kq_[(32 + l15) * 64 + ((32 + quad * 8) ^ swr)];    \
    kb3 = *(const s16x8*)&Kq_[(48 + l15) * 64 + ((32 + quad * 8) ^ swr)];    \
  } while (0)

#define QK_MFMA(S0_, S1_, S2_, S3_) do {                                     \
    f32x4 z_ = {};                                                           \
    z_ = mfma_bf16(qf0, ka0, z_); S0_ = mfma_bf16(qf1, kb0, z_);             \
    z_ = (f32x4){};                                                          \
    z_ = mfma_bf16(qf0, ka1, z_); S1_ = mfma_bf16(qf1, kb1, z_);             \
    z_ = (f32x4){};                                                          \
    z_ = mfma_bf16(qf0, ka2, z_); S2_ = mfma_bf16(qf1, kb2, z_);             \
    z_ = (f32x4){};                                                          \
    z_ = mfma_bf16(qf0, ka3, z_); S3_ = mfma_bf16(qf1, kb3, z_);             \
  } while (0)

#define SMAXPV(J, S0_, S1_, S2_, S3_) do {                                   \
    if ((J) == nt - 1) {  /* diagonal tile only */                           \
      _Pragma("unroll") for (int reg = 0; reg < 4; ++reg) {                  \
        const int qrow_ = qb + (w << 4) + quad * 4 + reg;                    \
        const int k0_ = ((J) << 6) + l15;                                    \
        if (k0_ +  0 > qrow_) S0_[reg] = -1e30f;                             \
        if (k0_ + 16 > qrow_) S1_[reg] = -1e30f;                             \
        if (k0_ + 32 > qrow_) S2_[reg] = -1e30f;                             \
        if (k0_ + 48 > qrow_) S3_[reg] = -1e30f;                             \
      }                                                                      \
    }                                                                        \
    float mx_[4];                                                            \
    _Pragma("unroll") for (int reg = 0; reg < 4; ++reg)                      \
      mx_[reg] = fmaxf(fmaxf(S0_[reg], S1_[reg]), fmaxf(S2_[reg], S3_[reg]));\
    _Pragma("unroll") for (int off = 1; off < 16; off <<= 1)                 \
      _Pragma("unroll") for (int reg = 0; reg < 4; ++reg)                    \
        mx_[reg] = fmaxf(mx_[reg], __shfl_xor(mx_[reg], off, 64));           \
    bool up_ = false;                                                        \
    _Pragma("unroll") for (int reg = 0; reg < 4; ++reg)                      \
      up_ = up_ || (mx_[reg] > m_i[reg] + 8.f);                              \
    if (__any(up_)) {  /* defer-max (T13): rescale only on real growth */    \
      _Pragma("unroll") for (int reg = 0; reg < 4; ++reg) {                  \
        const float nm_ = fmaxf(m_i[reg], mx_[reg]);                         \
        const float al_ = __expf(m_i[reg] - nm_);                            \
        m_i[reg] = nm_; l_p[reg] *= al_;                                     \
        o[0][reg] *= al_; o[1][reg] *= al_;                                  \
        o[2][reg] *= al_; o[3][reg] *= al_;                                  \
      }                                                                      \
    }                                                                        \
    _Pragma("unroll") for (int reg = 0; reg < 4; ++reg) {                    \
      const float e0_ = __expf(S0_[reg] - m_i[reg]);                         \
      const float e1_ = __expf(S1_[reg] - m_i[reg]);                         \
      const float e2_ = __expf(S2_[reg] - m_i[reg]);                         \
      const float e3_ = __expf(S3_[reg] - m_i[reg]);                         \
      l_p[reg] += e0_ + e1_ + e2_ + e3_;                                     \
      const int row_ = quad * 4 + reg;                                       \
      bf16* pr_ = &Ps[w][row_ * 64];                                         \
      const int sx_ = (row_ & 7) << 3;                                       \
      pr_[( 0 + l15) ^ sx_] = __float2bfloat16(e0_);                         \
      pr_[(16 + l15) ^ sx_] = __float2bfloat16(e1_);                         \
      pr_[(32 + l15) ^ sx_] = __float2bfloat16(e2_);                         \
      pr_[(48 + l15) ^ sx_] = __float2bfloat16(e3_);                         \
    }                                                                        \
    {                                                                        \
      const bf16* Vc_ = Vt[(J) & 1];                                         \
      _Pragma("unroll") for (int ks = 0; ks < 2; ++ks) {                     \
        const s16x8 pf_ =                                                    \
            *(const s16x8*)&Ps[w][l15 * 64 + ((ks * 32 + quad * 8) ^ swr)];  \
        _Pragma("unroll") for (int ni = 0; ni < 4; ++ni) {                   \
          const s16x8 vf_ = *(const s16x8*)                                  \
              &Vc_[(ni * 16 + l15) * 64 + ((ks * 32 + quad * 8) ^ swr)];     \
          o[ni] = mfma_bf16(pf_, vf_, o[ni]);                                \
        }                                                                    \
      }                                                                      \
    }                                                                        \
  } while (0)

#define BODY(KT, SO0, SO1, SO2, SO3, SN0, SN1, SN2, SN3) do {                \
    WRITEKV(KT);                                                             \
    BAR_SYNC();                                                              \
    if ((KT) + 1 < nt) ISSUE((KT) + 1);                                      \
    QK_LOAD(KT);                                                             \
    QK_MFMA(SN0, SN1, SN2, SN3);                                             \
    SMAXPV((KT) - 1, SO0, SO1, SO2, SO3);                                    \
    BAR_SYNC();                                                              \
  } while (0)

__global__ __launch_bounds__(256, 2) void flash_attn(
    const bf16* __restrict__ Q, const bf16* __restrict__ Kk,
    const bf16* __restrict__ V, bf16* __restrict__ O) {
  const int bxp = blockIdx.x;                 // 0..15: q-tile pair id
  const int h = blockIdx.y, b = blockIdx.z;
  const int t = threadIdx.x, w = t >> 6, l = t & 63;
  const int l15 = l & 15, quad = l >> 4;
  __shared__ __align__(16) bf16 Ks[2][64 * 64];    // [buf][key][d] swizzled
  __shared__ __align__(16) bf16 Vt[2][64 * 64];    // [buf][d][key] swizzled
  __shared__ __align__(16) bf16 Ps[4][16 * 64];    // per-wave P, swizzled

  // K staging: linear global chunk; swizzle applied at ds_write dest.
  const int krow = t >> 3;                    // 0..31
  const int kchunk = (t & 7) ^ (krow & 7);    // swizzled LDS chunk
  const bf16* Kg  = Kk + (size_t)(b * S_ + krow) * D_ + h * HD_ + ((t & 7) << 3);
  const bf16* Kg2 = Kg + (size_t)32 * D_;
  const int vk = t & 63, vd = w << 4;
  const bf16* Vg = V + (size_t)(b * S_ + vk) * D_ + h * HD_ + vd;
  const int swr = (l15 & 7) << 3;             // read-side xor (elements)

  s16x8 kr0, kr1, vr0, vr1;                   // staging regs (1 tile)
  s16x8 ka0, ka1, ka2, ka3, kb0, kb1, kb2, kb3;  // K fragment regs

#pragma unroll 1
  for (int ph = 0; ph < 2; ++ph) {
    const int qt = ph ? (S_ / 64 - 1 - bxp) : bxp;
    const int qb = qt << 6;
    const int nt = qt + 1;

    __syncthreads();   // protect LDS reuse across phases (full drain, 2x total)

    const bf16* qp =
        Q + (size_t)(b * S_ + qb + (w << 4) + l15) * D_ + h * HD_ + quad * 8;
    const s16x8 qf0 = *(const s16x8*)qp;
    const s16x8 qf1 = *(const s16x8*)(qp + 32);

    f32x4 o[4] = {};
    float m_i[4], l_p[4];
#pragma unroll
    for (int r = 0; r < 4; ++r) { m_i[r] = -1e30f; l_p[r] = 0.f; }

    f32x4 sA0, sA1, sA2, sA3, sB0, sB1, sB2, sB3;

    // ---- prologue: tile 0 ----
    ISSUE(0);
    WRITEKV(0);                  // counted vmcnt waits for kr/vr (cold, once)
    BAR_SYNC();
    if (nt > 1) ISSUE(1);
    QK_LOAD(0);
    QK_MFMA(sA0, sA1, sA2, sA3);
    BAR_SYNC();

    // ---- main loop: 2-stage score pipeline, hand-unrolled ping-pong ----
    int kt = 1;
    for (; kt + 1 < nt; kt += 2) {
      BODY(kt,     sA0, sA1, sA2, sA3, sB0, sB1, sB2, sB3);
      BODY(kt + 1, sB0, sB1, sB2, sB3, sA0, sA1, sA2, sA3);
    }
    if (kt < nt) {
      BODY(kt, sA0, sA1, sA2, sA3, sB0, sB1, sB2, sB3);
      SMAXPV(nt - 1, sB0, sB1, sB2, sB3);
    } else {
      SMAXPV(nt - 1, sA0, sA1, sA2, sA3);
    }

    // ---- epilogue: deferred l reduction + O write ----
    float inv[4];
#pragma unroll
    for (int off = 1; off < 16; off <<= 1)
#pragma unroll
      for (int reg = 0; reg < 4; ++reg)
        l_p[reg] += __shfl_xor(l_p[reg], off, 64);
#pragma unroll
    for (int reg = 0; reg < 4; ++reg) inv[reg] = 1.f / l_p[reg];

#pragma unroll
    for (int reg = 0; reg < 4; ++reg) {
      const int row = b * S_ + qb + (w << 4) + quad * 4 + reg;
      bf16* op = O + (size_t)row * D_ + h * HD_ + l15;
#pragma unroll
      for (int ni = 0; ni < 4; ++ni)
        op[ni * 16] = __float2bfloat16(o[ni][reg] * inv[reg]);
    }
  }
}

// ---------------------------------------------------------------------------
// LN1: h1 = LN(x_f32 + y1_bf16) -> bf16.   LN2: out = LN(sum_f32) -> fp32
// (in place). One block per 1024-col row.
// ---------------------------------------------------------------------------
template <int MODE>   // 0: LN1, 1: LN2
__global__ __launch_bounds__(256) void add_ln(
    const float* __restrict__ X, const bf16* __restrict__ Y,
    const float* __restrict__ g, const float* __restrict__ be,
    void* Out) {
  const int row = blockIdx.x, t = threadIdx.x;
  const size_t base = (size_t)row * D_ + t * 4;
  float v[4];
  float s = 0.f, q = 0.f;
#pragma unroll
  for (int i = 0; i < 4; ++i) {
    v[i] = X[base + i];
    if (MODE == 0) v[i] += b2f(*(const short*)&Y[base + i]);
    s += v[i];
    q += v[i] * v[i];
  }
#pragma unroll
  for (int off = 32; off; off >>= 1) {
    s += __shfl_down(s, off, 64);
    q += __shfl_down(q, off, 64);
  }
  __shared__ float rs[4], rq[4];
  const int w = t >> 6, l = t & 63;
  if (l == 0) { rs[w] = s; rq[w] = q; }
  __syncthreads();
  s = rs[0] + rs[1] + rs[2] + rs[3];
  q = rq[0] + rq[1] + rq[2] + rq[3];
  const float mu = s * (1.f / D_);
  const float var = q * (1.f / D_) - mu * mu;
  const float rstd = rsqrtf(var + 1e-5f);
#pragma unroll
  for (int i = 0; i < 4; ++i) {
    const float r = (v[i] - mu) * rstd * g[t * 4 + i] + be[t * 4 + i];
    if (MODE == 0) ((bf16*)Out)[base + i] = __float2bfloat16(r);
    else           ((float*)Out)[base + i] = r;
  }
}

extern "C" void kernel_launch(void* const* d_in, const int* in_sizes, int n_in,
                              void* d_out, int out_size, void* d_ws, size_t ws_size,
                              hipStream_t stream) {
  const float* x     = (const float*)d_in[0];
  const float* qkv_b = (const float*)d_in[2];
  const float* out_b = (const float*)d_in[4];
  const float* b1    = (const float*)d_in[6];
  const float* b2    = (const float*)d_in[8];
  const float* l1w   = (const float*)d_in[9];
  const float* l1b   = (const float*)d_in[10];
  const float* l2w   = (const float*)d_in[11];
  const float* l2b   = (const float*)d_in[12];

  float* out    = (float*)d_out;
  float* kcache = out + (size_t)M_ * D_;
  float* vcache = kcache + (size_t)M_ * D_;

  // ws (bf16 elems). High-water 28M elems = 56 MB (<75 MB established safe).
  //  [0,4M)   xc      -> attnb (after QKV)
  //  [4,7M)   wqkv    -> h1 (after out-proj; h1 spans [4,8M))
  //  [7,8M)   wout
  //  [8,12M)  w1c
  //  [12,16M) w2c
  //  [16,20M) qbuf    -> y1 (after flash)
  //  [20,24M) kb      -> ffb chunk (after flash; ffb spans [20,28M))
  //  [24,28M) vb
  bf16* ws    = (bf16*)d_ws;
  bf16* xc    = ws;
  bf16* attnb = ws;
  bf16* wqkv  = ws + 4 * MEG;
  bf16* h1    = ws + 4 * MEG;
  bf16* wout  = ws + 7 * MEG;
  bf16* w1c   = ws + 8 * MEG;
  bf16* w2c   = ws + 12 * MEG;
  bf16* qbuf  = ws + 16 * MEG;
  bf16* y1    = ws + 16 * MEG;
  bf16* kb    = ws + 20 * MEG;
  bf16* ffb   = ws + 20 * MEG;
  bf16* vb    = ws + 24 * MEG;

  const dim3 blk(256);
  auto cvt = [&](const void* src, bf16* dst, int n) {
    cvt_f2b<<<dim3((n + 2047) / 2048), blk, 0, stream>>>((const float*)src, dst, n);
  };
  cvt(d_in[0], xc,   M_ * D_);
  cvt(d_in[1], wqkv, 3 * D_ * D_);
  cvt(d_in[3], wout, D_ * D_);
  cvt(d_in[5], w1c,  FFD_ * D_);
  cvt(d_in[7], w2c,  D_ * FFD_);

  // QKV: q (pre-scaled 0.125) -> qbuf bf16; k/v->fp32 caches + bf16 ws copies.
  gemm_bt<3><<<dim3(3 * D_ / 128, M_ / 128), blk, 0, stream>>>(
      xc, wqkv, qkv_b, qbuf, nullptr, kcache, kb, vcache, vb, nullptr,
      M_, 3 * D_, D_);
  flash_attn<<<dim3(S_ / 128, H_, B_), blk, 0, stream>>>(qbuf, kb, vb, attnb);
  // out-proj -> y1 bf16 (overwrites dead qbuf)
  gemm_bt<0><<<dim3(D_ / 128, M_ / 128), blk, 0, stream>>>(
      attnb, wout, out_b, y1, nullptr, nullptr, nullptr, nullptr, nullptr,
      nullptr, M_, D_, D_);
  // h1 = LN(x + y1) -> bf16 (overwrites dead wqkv)
  add_ln<0><<<dim3(M_), blk, 0, stream>>>(x, y1, l1w, l1b, h1);
  // MLP, 2 chunks of 2048 rows; ffb reuses kb/vb region; sum -> d_out fp32.
  for (int c = 0; c < 2; ++c) {
    const bf16* hrows = h1 + (size_t)c * 2048 * D_;
    float* srows = out + (size_t)c * 2048 * D_;
    gemm_bt<1><<<dim3(FFD_ / 128, 2048 / 128), blk, 0, stream>>>(
        hrows, w1c, b1, ffb, nullptr, nullptr, nullptr, nullptr, nullptr,
        nullptr, 2048, FFD_, D_);
    gemm_bt<2><<<dim3(D_ / 128, 2048 / 128), blk, 0, stream>>>(
        ffb, w2c, b2, nullptr, srows, nullptr, nullptr, nullptr, nullptr,
        hrows, 2048, D_, FFD_);
  }
  // out = LN(sum) in place, fp32.
  add_ln<1><<<dim3(M_), blk, 0, stream>>>(out, nullptr, l2w, l2b, out);
}

// Round 4
// 418.276 us; speedup vs baseline: 1.4808x; 1.2406x over previous
//
#include <hip/hip_runtime.h>
#include <hip/hip_bf16.h>
#include <stdint.h>

typedef __hip_bfloat16 bf16;
typedef __attribute__((ext_vector_type(8))) short s16x8;
typedef __attribute__((ext_vector_type(4))) float f32x4;

#define B_   2
#define S_   2048
#define D_   1024
#define H_   16
#define HD_  64
#define FFD_ 4096
#define M_   4096
#define MEG  ((size_t)1048576)

__device__ __forceinline__ f32x4 mfma_bf16(s16x8 a, s16x8 b, f32x4 c) {
  return __builtin_amdgcn_mfma_f32_16x16x32_bf16(a, b, c, 0, 0, 0);
}

__device__ __forceinline__ void gl_lds16(const bf16* g, bf16* l) {
  __builtin_amdgcn_global_load_lds(
      (const __attribute__((address_space(1))) void*)g,
      (__attribute__((address_space(3))) void*)l, 16, 0, 0);
}

__device__ __forceinline__ float b2f(short u) {
  union { uint32_t i; float f; } z;
  z.i = ((uint32_t)(unsigned short)u) << 16;
  return z.f;
}
__device__ __forceinline__ short f2b(float f) {
  const bf16 h = __float2bfloat16(f);
  return *(const short*)&h;
}

// ---------------------------------------------------------------------------
// fp32 -> bf16 conversion (inputs are fp32; GEMM operands need bf16).
// ---------------------------------------------------------------------------
__global__ __launch_bounds__(256) void cvt_f2b(
    const float* __restrict__ src, bf16* __restrict__ dst, int n) {
  const int idx = (blockIdx.x * 256 + threadIdx.x) * 8;
  if (idx >= n) return;
  s16x8 o;
#pragma unroll
  for (int i = 0; i < 8; ++i) o[i] = f2b(src[idx + i]);
  *(s16x8*)(dst + idx) = o;
}

// ---------------------------------------------------------------------------
// MFMA NT GEMM: C[m,n] = sum_k A[m,k]*W[n,k] + bias[n]  (bias fp32)
// 128x128 tile, BK=32, 4 waves (2x2), 4x4 16x16x32 frags.
// MODE 0: C -> bf16 Cb             (out-proj -> y1)
// MODE 1: relu, C -> bf16 Cb       (MLP1 -> ff)
// MODE 2: SPLIT-K=2 (gridDim.z=2). z=0: K-half-0 + bias + resid -> fp32 Cf.
//         z=1: K-half-1 raw partial -> fp32 Kf (rows<2048) / Vf (rows>=2048).
//         LN2 sums Cf + partial. Fixes CU starvation (128->512 blocks).
// MODE 3: QKV split: seg0 q*0.125 -> bf16 Cb (pre-scaled for attn);
//         seg1 k->fp32 Kf + bf16 Kb; seg2 v->fp32 Vf + bf16 Vb.
// ---------------------------------------------------------------------------
template <int MODE>
__global__ __launch_bounds__(256) void gemm_bt(
    const bf16* __restrict__ A, const bf16* __restrict__ W,
    const float* __restrict__ bias,
    bf16* __restrict__ Cb, float* __restrict__ Cf,
    float* __restrict__ Kf, bf16* __restrict__ Kb,
    float* __restrict__ Vf, bf16* __restrict__ Vb,
    const bf16* __restrict__ Res,
    int M, int N, int K) {
  __shared__ __align__(16) bf16 As[128 * 32];
  __shared__ __align__(16) bf16 Bs[128 * 32];
  const int t = threadIdx.x;
  const int m0 = blockIdx.y << 7, n0 = blockIdx.x << 7;
  const int w = t >> 6, l = t & 63;
  const int wm = (w >> 1) << 6, wn = (w & 1) << 6;
  const int l15 = l & 15, quad = l >> 4;

  const int kz   = (MODE == 2) ? (int)blockIdx.z : 0;   // K-split index
  const int Keff = (MODE == 2) ? (K >> 1) : K;

  f32x4 acc[4][4] = {};

  const int srow = t >> 2;          // 0..63
  const int scol = (t & 3) << 3;    // 0,8,16,24
  const bf16* Ag  = A + (size_t)(m0 + srow) * K + kz * Keff + scol;
  const bf16* Ag2 = Ag + ((size_t)K << 6);   // +64 rows
  const bf16* Wg  = W + (size_t)(n0 + srow) * K + kz * Keff + scol;
  const bf16* Wg2 = Wg + ((size_t)K << 6);
  bf16* Al  = As + t * 8;
  bf16* Al2 = Al + 2048;
  bf16* Bl  = Bs + t * 8;
  bf16* Bl2 = Bl + 2048;

  for (int k0 = 0; k0 < Keff; k0 += 32) {
    __syncthreads();
    gl_lds16(Ag + k0, Al);
    gl_lds16(Ag2 + k0, Al2);
    gl_lds16(Wg + k0, Bl);
    gl_lds16(Wg2 + k0, Bl2);
    __syncthreads();
    const s16x8* As8 = (const s16x8*)As;
    const s16x8* Bs8 = (const s16x8*)Bs;
    s16x8 af[4], bfr[4];
#pragma unroll
    for (int i = 0; i < 4; ++i) af[i]  = As8[((wm + i * 16 + l15) << 2) + quad];
#pragma unroll
    for (int i = 0; i < 4; ++i) bfr[i] = Bs8[((wn + i * 16 + l15) << 2) + quad];
#pragma unroll
    for (int mi = 0; mi < 4; ++mi)
#pragma unroll
      for (int ni = 0; ni < 4; ++ni)
        acc[mi][ni] = mfma_bf16(af[mi], bfr[ni], acc[mi][ni]);
  }

  float bv[4];
#pragma unroll
  for (int ni = 0; ni < 4; ++ni)
    bv[ni] = bias[n0 + wn + ni * 16 + l15];

  const int seg = n0 >> 10, nb = n0 & 1023;
#pragma unroll
  for (int mi = 0; mi < 4; ++mi) {
#pragma unroll
    for (int reg = 0; reg < 4; ++reg) {
      const int row = m0 + wm + mi * 16 + quad * 4 + reg;
#pragma unroll
      for (int ni = 0; ni < 4; ++ni) {
        float v = acc[mi][ni][reg] + ((MODE == 2 && kz) ? 0.f : bv[ni]);
        if (MODE == 0) {
          Cb[(size_t)row * N + n0 + wn + ni * 16 + l15] = __float2bfloat16(v);
        } else if (MODE == 1) {
          v = fmaxf(v, 0.f);
          Cb[(size_t)row * N + n0 + wn + ni * 16 + l15] = __float2bfloat16(v);
        } else if (MODE == 2) {
          const size_t col = n0 + wn + ni * 16 + l15;
          if (kz == 0) {
            const size_t o = (size_t)row * N + col;
            Cf[o] = v + b2f(*(const short*)&Res[o]);
          } else {
            float* P = (row < 2048) ? Kf : Vf;   // partial bufs (dead ws)
            P[(size_t)(row & 2047) * N + col] = v;
          }
        } else {  // MODE 3
          const size_t o = (size_t)row * 1024 + nb + wn + ni * 16 + l15;
          if (seg == 0) {
            Cb[o] = __float2bfloat16(v * 0.125f);   // pre-scale Q by 1/sqrt(hd)
          } else if (seg == 1) {
            Kf[o] = v; Kb[o] = __float2bfloat16(v);
          } else {
            Vf[o] = v; Vb[o] = __float2bfloat16(v);
          }
        }
      }
    }
  }
}

// ---------------------------------------------------------------------------
// MFMA flash attention v4, causal, hd=64.
// Block = (q-tile PAIR {bxp, 31-bxp}, head, batch): every block does exactly
// 33 k-tiles -> perfect inter-CU balance. Grid 16x16x2 = 512 blocks, 2/CU.
// K and V both reg-staged (global->reg->swizzled ds_write): no vmcnt drain at
// barriers (T4); only counted waits at WRITEKV, one iteration after issue.
// Named score regs (no lambdas/ref-arrays) => no scratch.
// Swizzle: elem col ^= (row&7)<<3 on Ks/Vt/Ps (bank-conflict-free).
// ---------------------------------------------------------------------------
#define BAR_SYNC() do {                                                      \
    asm volatile("s_waitcnt lgkmcnt(0)" ::: "memory");                       \
    __builtin_amdgcn_s_barrier();                                            \
    __builtin_amdgcn_sched_barrier(0);                                       \
  } while (0)

#define ISSUE(KT) do { const size_t ko_ = (size_t)((KT) << 6) * D_;          \
    kr0 = *(const s16x8*)(Kg + ko_);                                         \
    kr1 = *(const s16x8*)(Kg2 + ko_);                                        \
    vr0 = *(const s16x8*)(Vg + ko_);                                         \
    vr1 = *(const s16x8*)(Vg + ko_ + 8);                                     \
  } while (0)

#define WRITEKV(KT) do {                                                     \
    bf16* kd_ = Ks[(KT) & 1];                                                \
    *(s16x8*)&kd_[krow * 64 + (kchunk << 3)] = kr0;                          \
    *(s16x8*)&kd_[(krow + 32) * 64 + (kchunk << 3)] = kr1;                   \
    short* vp_ = (short*)Vt[(KT) & 1];                                       \
    _Pragma("unroll") for (int j = 0; j < 8; ++j) {                          \
      const int d0_ = vd + j, d1_ = vd + 8 + j;                              \
      vp_[d0_ * 64 + (vk ^ ((d0_ & 7) << 3))] = vr0[j];                      \
      vp_[d1_ * 64 + (vk ^ ((d1_ & 7) << 3))] = vr1[j];                      \
    }                                                                        \
  } while (0)

#define QK_LOAD(KT) do { const bf16* Kq_ = Ks[(KT) & 1];                     \
    ka0 = *(const s16x8*)&Kq_[( 0 + l15) * 64 + (( 0 + quad * 8) ^ swr)];    \
    ka1 = *(const s16x8*)&Kq_[(16 + l15) * 64 + (( 0 + quad * 8) ^ swr)];    \
    ka2 = *(const s16x8*)&Kq_[(32 + l15) * 64 + (( 0 + quad * 8) ^ swr)];    \
    ka3 = *(const s16x8*)&Kq_[(48 + l15) * 64 + (( 0 + quad * 8) ^ swr)];    \
    kb0 = *(const s16x8*)&Kq_[( 0 + l15) * 64 + ((32 + quad * 8) ^ swr)];    \
    kb1 = *(const s16x8*)&Kq_[(16 + l15) * 64 + ((32 + quad * 8) ^ swr)];    \
    kb2 = *(const s16x8*)&Kq_[(32 + l15) * 64 + ((32 + quad * 8) ^ swr)];    \
    kb3 = *(const s16x8*)&Kq_[(48 + l15) * 64 + ((32 + quad * 8) ^ swr)];    \
  } while (0)

#define QK_MFMA(S0_, S1_, S2_, S3_) do {                                     \
    f32x4 z_ = {};                                                           \
    z_ = mfma_bf16(qf0, ka0, z_); S0_ = mfma_bf16(qf1, kb0, z_);             \
    z_ = (f32x4){};                                                          \
    z_ = mfma_bf16(qf0, ka1, z_); S1_ = mfma_bf16(qf1, kb1, z_);             \
    z_ = (f32x4){};                                                          \
    z_ = mfma_bf16(qf0, ka2, z_); S2_ = mfma_bf16(qf1, kb2, z_);             \
    z_ = (f32x4){};                                                          \
    z_ = mfma_bf16(qf0, ka3, z_); S3_ = mfma_bf16(qf1, kb3, z_);             \
  } while (0)

#define SMAXPV(J, S0_, S1_, S2_, S3_) do {                                   \
    if ((J) == nt - 1) {  /* diagonal tile only */                           \
      _Pragma("unroll") for (int reg = 0; reg < 4; ++reg) {                  \
        const int qrow_ = qb + (w << 4) + quad * 4 + reg;                    \
        const int k0_ = ((J) << 6) + l15;                                    \
        if (k0_ +  0 > qrow_) S0_[reg] = -1e30f;                             \
        if (k0_ + 16 > qrow_) S1_[reg] = -1e30f;                             \
        if (k0_ + 32 > qrow_) S2_[reg] = -1e30f;                             \
        if (k0_ + 48 > qrow_) S3_[reg] = -1e30f;                             \
      }                                                                      \
    }                                                                        \
    float mx_[4];                                                            \
    _Pragma("unroll") for (int reg = 0; reg < 4; ++reg)                      \
      mx_[reg] = fmaxf(fmaxf(S0_[reg], S1_[reg]), fmaxf(S2_[reg], S3_[reg]));\
    _Pragma("unroll") for (int off = 1; off < 16; off <<= 1)                 \
      _Pragma("unroll") for (int reg = 0; reg < 4; ++reg)                    \
        mx_[reg] = fmaxf(mx_[reg], __shfl_xor(mx_[reg], off, 64));           \
    bool up_ = false;                                                        \
    _Pragma("unroll") for (int reg = 0; reg < 4; ++reg)                      \
      up_ = up_ || (mx_[reg] > m_i[reg] + 8.f);                              \
    if (__any(up_)) {  /* defer-max (T13): rescale only on real growth */    \
      _Pragma("unroll") for (int reg = 0; reg < 4; ++reg) {                  \
        const float nm_ = fmaxf(m_i[reg], mx_[reg]);                         \
        const float al_ = __expf(m_i[reg] - nm_);                            \
        m_i[reg] = nm_; l_p[reg] *= al_;                                     \
        o[0][reg] *= al_; o[1][reg] *= al_;                                  \
        o[2][reg] *= al_; o[3][reg] *= al_;                                  \
      }                                                                      \
    }                                                                        \
    _Pragma("unroll") for (int reg = 0; reg < 4; ++reg) {                    \
      const float e0_ = __expf(S0_[reg] - m_i[reg]);                         \
      const float e1_ = __expf(S1_[reg] - m_i[reg]);                         \
      const float e2_ = __expf(S2_[reg] - m_i[reg]);                         \
      const float e3_ = __expf(S3_[reg] - m_i[reg]);                         \
      l_p[reg] += e0_ + e1_ + e2_ + e3_;                                     \
      const int row_ = quad * 4 + reg;                                       \
      bf16* pr_ = &Ps[w][row_ * 64];                                         \
      const int sx_ = (row_ & 7) << 3;                                       \
      pr_[( 0 + l15) ^ sx_] = __float2bfloat16(e0_);                         \
      pr_[(16 + l15) ^ sx_] = __float2bfloat16(e1_);                         \
      pr_[(32 + l15) ^ sx_] = __float2bfloat16(e2_);                         \
      pr_[(48 + l15) ^ sx_] = __float2bfloat16(e3_);                         \
    }                                                                        \
    {                                                                        \
      const bf16* Vc_ = Vt[(J) & 1];                                         \
      _Pragma("unroll") for (int ks = 0; ks < 2; ++ks) {                     \
        const s16x8 pf_ =                                                    \
            *(const s16x8*)&Ps[w][l15 * 64 + ((ks * 32 + quad * 8) ^ swr)];  \
        _Pragma("unroll") for (int ni = 0; ni < 4; ++ni) {                   \
          const s16x8 vf_ = *(const s16x8*)                                  \
              &Vc_[(ni * 16 + l15) * 64 + ((ks * 32 + quad * 8) ^ swr)];     \
          o[ni] = mfma_bf16(pf_, vf_, o[ni]);                                \
        }                                                                    \
      }                                                                      \
    }                                                                        \
  } while (0)

#define BODY(KT, SO0, SO1, SO2, SO3, SN0, SN1, SN2, SN3) do {                \
    WRITEKV(KT);                                                             \
    BAR_SYNC();                                                              \
    if ((KT) + 1 < nt) ISSUE((KT) + 1);                                      \
    QK_LOAD(KT);                                                             \
    QK_MFMA(SN0, SN1, SN2, SN3);                                             \
    SMAXPV((KT) - 1, SO0, SO1, SO2, SO3);                                    \
    BAR_SYNC();                                                              \
  } while (0)

__global__ __launch_bounds__(256, 2) void flash_attn(
    const bf16* __restrict__ Q, const bf16* __restrict__ Kk,
    const bf16* __restrict__ V, bf16* __restrict__ O) {
  const int bxp = blockIdx.x;                 // 0..15: q-tile pair id
  const int h = blockIdx.y, b = blockIdx.z;
  const int t = threadIdx.x, w = t >> 6, l = t & 63;
  const int l15 = l & 15, quad = l >> 4;
  __shared__ __align__(16) bf16 Ks[2][64 * 64];    // [buf][key][d] swizzled
  __shared__ __align__(16) bf16 Vt[2][64 * 64];    // [buf][d][key] swizzled
  __shared__ __align__(16) bf16 Ps[4][16 * 64];    // per-wave P, swizzled

  // K staging: linear global chunk; swizzle applied at ds_write dest.
  const int krow = t >> 3;                    // 0..31
  const int kchunk = (t & 7) ^ (krow & 7);    // swizzled LDS chunk
  const bf16* Kg  = Kk + (size_t)(b * S_ + krow) * D_ + h * HD_ + ((t & 7) << 3);
  const bf16* Kg2 = Kg + (size_t)32 * D_;
  const int vk = t & 63, vd = w << 4;
  const bf16* Vg = V + (size_t)(b * S_ + vk) * D_ + h * HD_ + vd;
  const int swr = (l15 & 7) << 3;             // read-side xor (elements)

  s16x8 kr0, kr1, vr0, vr1;                   // staging regs (1 tile)
  s16x8 ka0, ka1, ka2, ka3, kb0, kb1, kb2, kb3;  // K fragment regs

#pragma unroll 1
  for (int ph = 0; ph < 2; ++ph) {
    const int qt = ph ? (S_ / 64 - 1 - bxp) : bxp;
    const int qb = qt << 6;
    const int nt = qt + 1;

    __syncthreads();   // protect LDS reuse across phases (full drain, 2x total)

    const bf16* qp =
        Q + (size_t)(b * S_ + qb + (w << 4) + l15) * D_ + h * HD_ + quad * 8;
    const s16x8 qf0 = *(const s16x8*)qp;
    const s16x8 qf1 = *(const s16x8*)(qp + 32);

    f32x4 o[4] = {};
    float m_i[4], l_p[4];
#pragma unroll
    for (int r = 0; r < 4; ++r) { m_i[r] = -1e30f; l_p[r] = 0.f; }

    f32x4 sA0, sA1, sA2, sA3, sB0, sB1, sB2, sB3;

    // ---- prologue: tile 0 ----
    ISSUE(0);
    WRITEKV(0);                  // counted vmcnt waits for kr/vr (cold, once)
    BAR_SYNC();
    if (nt > 1) ISSUE(1);
    QK_LOAD(0);
    QK_MFMA(sA0, sA1, sA2, sA3);
    BAR_SYNC();

    // ---- main loop: 2-stage score pipeline, hand-unrolled ping-pong ----
    int kt = 1;
    for (; kt + 1 < nt; kt += 2) {
      BODY(kt,     sA0, sA1, sA2, sA3, sB0, sB1, sB2, sB3);
      BODY(kt + 1, sB0, sB1, sB2, sB3, sA0, sA1, sA2, sA3);
    }
    if (kt < nt) {
      BODY(kt, sA0, sA1, sA2, sA3, sB0, sB1, sB2, sB3);
      SMAXPV(nt - 1, sB0, sB1, sB2, sB3);
    } else {
      SMAXPV(nt - 1, sA0, sA1, sA2, sA3);
    }

    // ---- epilogue: deferred l reduction + O write ----
    float inv[4];
#pragma unroll
    for (int off = 1; off < 16; off <<= 1)
#pragma unroll
      for (int reg = 0; reg < 4; ++reg)
        l_p[reg] += __shfl_xor(l_p[reg], off, 64);
#pragma unroll
    for (int reg = 0; reg < 4; ++reg) inv[reg] = 1.f / l_p[reg];

#pragma unroll
    for (int reg = 0; reg < 4; ++reg) {
      const int row = b * S_ + qb + (w << 4) + quad * 4 + reg;
      bf16* op = O + (size_t)row * D_ + h * HD_ + l15;
#pragma unroll
      for (int ni = 0; ni < 4; ++ni)
        op[ni * 16] = __float2bfloat16(o[ni][reg] * inv[reg]);
    }
  }
}

// ---------------------------------------------------------------------------
// LN1 (MODE 0): h1 = LN(x_f32 + y1_bf16) -> bf16.
// LN2 (MODE 1): out = LN(X + PA/PB partial) -> fp32 in place (X=out holds
//               K-half-0 + bias + resid; PA/PB hold K-half-1 partial).
// One block per 1024-col row.
// ---------------------------------------------------------------------------
template <int MODE>   // 0: LN1, 1: LN2
__global__ __launch_bounds__(256) void add_ln(
    const float* __restrict__ X, const bf16* __restrict__ Y,
    const float* __restrict__ PA, const float* __restrict__ PB,
    const float* __restrict__ g, const float* __restrict__ be,
    void* Out) {
  const int row = blockIdx.x, t = threadIdx.x;
  const size_t base = (size_t)row * D_ + t * 4;
  const float* P = (MODE == 1)
      ? ((row < 2048) ? PA + base : PB + (base - (size_t)2048 * D_))
      : nullptr;
  float v[4];
  float s = 0.f, q = 0.f;
#pragma unroll
  for (int i = 0; i < 4; ++i) {
    v[i] = X[base + i];
    if (MODE == 0) v[i] += b2f(*(const short*)&Y[base + i]);
    else           v[i] += P[i];
    s += v[i];
    q += v[i] * v[i];
  }
#pragma unroll
  for (int off = 32; off; off >>= 1) {
    s += __shfl_down(s, off, 64);
    q += __shfl_down(q, off, 64);
  }
  __shared__ float rs[4], rq[4];
  const int w = t >> 6, l = t & 63;
  if (l == 0) { rs[w] = s; rq[w] = q; }
  __syncthreads();
  s = rs[0] + rs[1] + rs[2] + rs[3];
  q = rq[0] + rq[1] + rq[2] + rq[3];
  const float mu = s * (1.f / D_);
  const float var = q * (1.f / D_) - mu * mu;
  const float rstd = rsqrtf(var + 1e-5f);
#pragma unroll
  for (int i = 0; i < 4; ++i) {
    const float r = (v[i] - mu) * rstd * g[t * 4 + i] + be[t * 4 + i];
    if (MODE == 0) ((bf16*)Out)[base + i] = __float2bfloat16(r);
    else           ((float*)Out)[base + i] = r;
  }
}

extern "C" void kernel_launch(void* const* d_in, const int* in_sizes, int n_in,
                              void* d_out, int out_size, void* d_ws, size_t ws_size,
                              hipStream_t stream) {
  const float* x     = (const float*)d_in[0];
  const float* qkv_b = (const float*)d_in[2];
  const float* out_b = (const float*)d_in[4];
  const float* b1    = (const float*)d_in[6];
  const float* b2    = (const float*)d_in[8];
  const float* l1w   = (const float*)d_in[9];
  const float* l1b   = (const float*)d_in[10];
  const float* l2w   = (const float*)d_in[11];
  const float* l2b   = (const float*)d_in[12];

  float* out    = (float*)d_out;
  float* kcache = out + (size_t)M_ * D_;
  float* vcache = kcache + (size_t)M_ * D_;

  // ws (bf16 elems). High-water 36M elems = 72 MB (<75 MB established safe).
  //  [0,4M)   xc      -> attnb (after QKV) -> pA fp32 partial (after outproj)
  //  [4,7M)   wqkv    -> h1 (after out-proj; h1 spans [4,8M))
  //  [7,8M)   wout
  //  [8,12M)  w1c
  //  [12,16M) w2c
  //  [16,20M) qbuf    -> y1 (after flash) -> pB fp32 partial (after ln1)
  //  [20,24M) kb      -> ffb (after flash; full ffb spans [20,36M))
  //  [24,28M) vb
  bf16* ws    = (bf16*)d_ws;
  bf16* xc    = ws;
  bf16* attnb = ws;
  bf16* wqkv  = ws + 4 * MEG;
  bf16* h1    = ws + 4 * MEG;
  bf16* wout  = ws + 7 * MEG;
  bf16* w1c   = ws + 8 * MEG;
  bf16* w2c   = ws + 12 * MEG;
  bf16* qbuf  = ws + 16 * MEG;
  bf16* y1    = ws + 16 * MEG;
  bf16* kb    = ws + 20 * MEG;
  bf16* ffb   = ws + 20 * MEG;
  bf16* vb    = ws + 24 * MEG;
  float* pA   = (float*)ws;               // rows 0..2047  K-half-1 partial
  float* pB   = (float*)(ws + 16 * MEG);  // rows 2048..4095

  const dim3 blk(256);
  auto cvt = [&](const void* src, bf16* dst, int n) {
    cvt_f2b<<<dim3((n + 2047) / 2048), blk, 0, stream>>>((const float*)src, dst, n);
  };
  cvt(d_in[0], xc,   M_ * D_);
  cvt(d_in[1], wqkv, 3 * D_ * D_);
  cvt(d_in[3], wout, D_ * D_);
  cvt(d_in[5], w1c,  FFD_ * D_);
  cvt(d_in[7], w2c,  D_ * FFD_);

  // QKV: q (pre-scaled 0.125) -> qbuf bf16; k/v->fp32 caches + bf16 ws copies.
  gemm_bt<3><<<dim3(3 * D_ / 128, M_ / 128), blk, 0, stream>>>(
      xc, wqkv, qkv_b, qbuf, nullptr, kcache, kb, vcache, vb, nullptr,
      M_, 3 * D_, D_);
  flash_attn<<<dim3(S_ / 128, H_, B_), blk, 0, stream>>>(qbuf, kb, vb, attnb);
  // out-proj -> y1 bf16 (overwrites dead qbuf)
  gemm_bt<0><<<dim3(D_ / 128, M_ / 128), blk, 0, stream>>>(
      attnb, wout, out_b, y1, nullptr, nullptr, nullptr, nullptr, nullptr,
      nullptr, M_, D_, D_);
  // h1 = LN(x + y1) -> bf16 (overwrites dead wqkv)
  add_ln<0><<<dim3(M_), blk, 0, stream>>>(x, y1, nullptr, nullptr, l1w, l1b, h1);
  // MLP full-M (un-chunked): MLP1 -> ffb [20,36M); MLP2 split-K=2:
  // z=0 K-half-0 + bias + resid -> out; z=1 K-half-1 raw -> pA/pB.
  gemm_bt<1><<<dim3(FFD_ / 128, M_ / 128), blk, 0, stream>>>(
      h1, w1c, b1, ffb, nullptr, nullptr, nullptr, nullptr, nullptr,
      nullptr, M_, FFD_, D_);
  gemm_bt<2><<<dim3(D_ / 128, M_ / 128, 2), blk, 0, stream>>>(
      ffb, w2c, b2, nullptr, out, pA, nullptr, pB, nullptr,
      h1, M_, D_, FFD_);
  // out = LN(out + partial) in place, fp32.
  add_ln<1><<<dim3(M_), blk, 0, stream>>>(out, nullptr, pA, pB, l2w, l2b, out);
}

// Round 5
// 387.409 us; speedup vs baseline: 1.5988x; 1.0797x over previous
//
#include <hip/hip_runtime.h>
#include <hip/hip_bf16.h>
#include <stdint.h>

typedef __hip_bfloat16 bf16;
typedef __attribute__((ext_vector_type(8))) short s16x8;
typedef __attribute__((ext_vector_type(4))) float f32x4;

#define B_   2
#define S_   2048
#define D_   1024
#define H_   16
#define HD_  64
#define FFD_ 4096
#define M_   4096
#define MEG  ((size_t)1048576)

__device__ __forceinline__ f32x4 mfma_bf16(s16x8 a, s16x8 b, f32x4 c) {
  return __builtin_amdgcn_mfma_f32_16x16x32_bf16(a, b, c, 0, 0, 0);
}

__device__ __forceinline__ void gl_lds16(const bf16* g, bf16* l) {
  __builtin_amdgcn_global_load_lds(
      (const __attribute__((address_space(1))) void*)g,
      (__attribute__((address_space(3))) void*)l, 16, 0, 0);
}

__device__ __forceinline__ float b2f(short u) {
  union { uint32_t i; float f; } z;
  z.i = ((uint32_t)(unsigned short)u) << 16;
  return z.f;
}
__device__ __forceinline__ short f2b(float f) {
  const bf16 h = __float2bfloat16(f);
  return *(const short*)&h;
}

// ---------------------------------------------------------------------------
// fp32 -> bf16 conversion, all 5 tensors in ONE dispatch (z-indexed).
// ---------------------------------------------------------------------------
struct CvtArgs {
  const float* src[5];
  bf16* dst[5];
  int n[5];
};
__global__ __launch_bounds__(256) void cvt_f2b_multi(CvtArgs a) {
  const int z = blockIdx.y;
  const int idx = (blockIdx.x * 256 + threadIdx.x) * 8;
  if (idx >= a.n[z]) return;
  const float* src = a.src[z];
  s16x8 o;
#pragma unroll
  for (int i = 0; i < 8; ++i) o[i] = f2b(src[idx + i]);
  *(s16x8*)(a.dst[z] + idx) = o;
}

// ---------------------------------------------------------------------------
// MFMA NT GEMM: C[m,n] = sum_k A[m,k]*W[n,k] + bias[n]  (bias fp32)
// 128x128 tile, BK=32, 4 waves (2x2), 4x4 16x16x32 frags.
// v2: (a) 2-phase double-buffered K-loop — stage(t+1) issued BEFORE the
//     ds_read+MFMA of tile t; ONE __syncthreads per K-step (its vmcnt drain
//     lands after ~500cy of compute cover, not right after issue).
//     (b) T1 XCD-chunked block swizzle — each XCD owns contiguous m-rows so
//     each A-panel is fetched by exactly one XCD (was 8x refetch, 139 MB).
// MODE 0: C -> bf16 Cb             (out-proj -> y1)
// MODE 1: relu, C -> bf16 Cb       (MLP1 -> ff)
// MODE 2: SPLIT-K=2 (gridDim.z=2). z=0: K-half-0 + bias + resid -> fp32 Cf.
//         z=1: K-half-1 raw partial -> fp32 Kf (rows<2048) / Vf (rows>=2048).
// MODE 3: QKV split: seg0 q*0.125 -> bf16 Cb (pre-scaled for attn);
//         seg1 k->fp32 Kf + bf16 Kb; seg2 v->fp32 Vf + bf16 Vb.
// ---------------------------------------------------------------------------
template <int MODE>
__global__ __launch_bounds__(256) void gemm_bt(
    const bf16* __restrict__ A, const bf16* __restrict__ W,
    const float* __restrict__ bias,
    bf16* __restrict__ Cb, float* __restrict__ Cf,
    float* __restrict__ Kf, bf16* __restrict__ Kb,
    float* __restrict__ Vf, bf16* __restrict__ Vb,
    const bf16* __restrict__ Res,
    int M, int N, int K) {
  __shared__ __align__(16) bf16 As[2][128 * 32];
  __shared__ __align__(16) bf16 Bs[2][128 * 32];
  const int t = threadIdx.x;

  // T1 XCD-chunked swizzle (all grids have nwg % 8 == 0 -> bijective).
  const int nwg = gridDim.x * gridDim.y;
  const int bid = blockIdx.y * gridDim.x + blockIdx.x;
  const int sw  = (bid & 7) * (nwg >> 3) + (bid >> 3);
  const int m0 = (sw / gridDim.x) << 7, n0 = (sw % gridDim.x) << 7;

  const int w = t >> 6, l = t & 63;
  const int wm = (w >> 1) << 6, wn = (w & 1) << 6;
  const int l15 = l & 15, quad = l >> 4;

  const int kz   = (MODE == 2) ? (int)blockIdx.z : 0;   // K-split index
  const int Keff = (MODE == 2) ? (K >> 1) : K;

  f32x4 acc[4][4] = {};

  const int srow = t >> 2;          // 0..63
  const int scol = (t & 3) << 3;    // 0,8,16,24
  const bf16* Ag  = A + (size_t)(m0 + srow) * K + kz * Keff + scol;
  const bf16* Ag2 = Ag + ((size_t)K << 6);   // +64 rows
  const bf16* Wg  = W + (size_t)(n0 + srow) * K + kz * Keff + scol;
  const bf16* Wg2 = Wg + ((size_t)K << 6);

  // prologue: stage K-step 0 into buffer 0
  {
    bf16* Ad = (bf16*)As[0] + t * 8;
    bf16* Bd = (bf16*)Bs[0] + t * 8;
    gl_lds16(Ag, Ad);
    gl_lds16(Ag2, Ad + 2048);
    gl_lds16(Wg, Bd);
    gl_lds16(Wg2, Bd + 2048);
  }
  __syncthreads();

  for (int k0 = 0; k0 < Keff; k0 += 32) {
    const int cur = (k0 >> 5) & 1;
    if (k0 + 32 < Keff) {          // issue next-tile stage into other buffer
      const int nb = cur ^ 1;
      bf16* Ad = (bf16*)As[nb] + t * 8;
      bf16* Bd = (bf16*)Bs[nb] + t * 8;
      gl_lds16(Ag + k0 + 32, Ad);
      gl_lds16(Ag2 + k0 + 32, Ad + 2048);
      gl_lds16(Wg + k0 + 32, Bd);
      gl_lds16(Wg2 + k0 + 32, Bd + 2048);
    }
    const s16x8* As8 = (const s16x8*)As[cur];
    const s16x8* Bs8 = (const s16x8*)Bs[cur];
    s16x8 af[4], bfr[4];
#pragma unroll
    for (int i = 0; i < 4; ++i) af[i]  = As8[((wm + i * 16 + l15) << 2) + quad];
#pragma unroll
    for (int i = 0; i < 4; ++i) bfr[i] = Bs8[((wn + i * 16 + l15) << 2) + quad];
#pragma unroll
    for (int mi = 0; mi < 4; ++mi)
#pragma unroll
      for (int ni = 0; ni < 4; ++ni)
        acc[mi][ni] = mfma_bf16(af[mi], bfr[ni], acc[mi][ni]);
    __syncthreads();               // drains vmcnt (next tile) + read WAR
  }

  float bv[4];
#pragma unroll
  for (int ni = 0; ni < 4; ++ni)
    bv[ni] = bias[n0 + wn + ni * 16 + l15];

  const int seg = n0 >> 10, nb2 = n0 & 1023;
#pragma unroll
  for (int mi = 0; mi < 4; ++mi) {
#pragma unroll
    for (int reg = 0; reg < 4; ++reg) {
      const int row = m0 + wm + mi * 16 + quad * 4 + reg;
#pragma unroll
      for (int ni = 0; ni < 4; ++ni) {
        float v = acc[mi][ni][reg] + ((MODE == 2 && kz) ? 0.f : bv[ni]);
        if (MODE == 0) {
          Cb[(size_t)row * N + n0 + wn + ni * 16 + l15] = __float2bfloat16(v);
        } else if (MODE == 1) {
          v = fmaxf(v, 0.f);
          Cb[(size_t)row * N + n0 + wn + ni * 16 + l15] = __float2bfloat16(v);
        } else if (MODE == 2) {
          const size_t col = n0 + wn + ni * 16 + l15;
          if (kz == 0) {
            const size_t o = (size_t)row * N + col;
            Cf[o] = v + b2f(*(const short*)&Res[o]);
          } else {
            float* P = (row < 2048) ? Kf : Vf;   // partial bufs (dead ws)
            P[(size_t)(row & 2047) * N + col] = v;
          }
        } else {  // MODE 3
          const size_t o = (size_t)row * 1024 + nb2 + wn + ni * 16 + l15;
          if (seg == 0) {
            Cb[o] = __float2bfloat16(v * 0.125f);   // pre-scale Q by 1/sqrt(hd)
          } else if (seg == 1) {
            Kf[o] = v; Kb[o] = __float2bfloat16(v);
          } else {
            Vf[o] = v; Vb[o] = __float2bfloat16(v);
          }
        }
      }
    }
  }
}

// ---------------------------------------------------------------------------
// MFMA flash attention v4, causal, hd=64.
// Block = (q-tile PAIR {bxp, 31-bxp}, head, batch): every block does exactly
// 33 k-tiles -> perfect inter-CU balance. Grid 16x16x2 = 512 blocks, 2/CU.
// K and V both reg-staged (global->reg->swizzled ds_write): no vmcnt drain at
// barriers (T4); only counted waits at WRITEKV, one iteration after issue.
// Named score regs (no lambdas/ref-arrays) => no scratch.
// Swizzle: elem col ^= (row&7)<<3 on Ks/Vt/Ps (bank-conflict-free).
// ---------------------------------------------------------------------------
#define BAR_SYNC() do {                                                      \
    asm volatile("s_waitcnt lgkmcnt(0)" ::: "memory");                       \
    __builtin_amdgcn_s_barrier();                                            \
    __builtin_amdgcn_sched_barrier(0);                                       \
  } while (0)

#define ISSUE(KT) do { const size_t ko_ = (size_t)((KT) << 6) * D_;          \
    kr0 = *(const s16x8*)(Kg + ko_);                                         \
    kr1 = *(const s16x8*)(Kg2 + ko_);                                        \
    vr0 = *(const s16x8*)(Vg + ko_);                                         \
    vr1 = *(const s16x8*)(Vg + ko_ + 8);                                     \
  } while (0)

#define WRITEKV(KT) do {                                                     \
    bf16* kd_ = Ks[(KT) & 1];                                                \
    *(s16x8*)&kd_[krow * 64 + (kchunk << 3)] = kr0;                          \
    *(s16x8*)&kd_[(krow + 32) * 64 + (kchunk << 3)] = kr1;                   \
    short* vp_ = (short*)Vt[(KT) & 1];                                       \
    _Pragma("unroll") for (int j = 0; j < 8; ++j) {                          \
      const int d0_ = vd + j, d1_ = vd + 8 + j;                              \
      vp_[d0_ * 64 + (vk ^ ((d0_ & 7) << 3))] = vr0[j];                      \
      vp_[d1_ * 64 + (vk ^ ((d1_ & 7) << 3))] = vr1[j];                      \
    }                                                                        \
  } while (0)

#define QK_LOAD(KT) do { const bf16* Kq_ = Ks[(KT) & 1];                     \
    ka0 = *(const s16x8*)&Kq_[( 0 + l15) * 64 + (( 0 + quad * 8) ^ swr)];    \
    ka1 = *(const s16x8*)&Kq_[(16 + l15) * 64 + (( 0 + quad * 8) ^ swr)];    \
    ka2 = *(const s16x8*)&Kq_[(32 + l15) * 64 + (( 0 + quad * 8) ^ swr)];    \
    ka3 = *(const s16x8*)&Kq_[(48 + l15) * 64 + (( 0 + quad * 8) ^ swr)];    \
    kb0 = *(const s16x8*)&Kq_[( 0 + l15) * 64 + ((32 + quad * 8) ^ swr)];    \
    kb1 = *(const s16x8*)&Kq_[(16 + l15) * 64 + ((32 + quad * 8) ^ swr)];    \
    kb2 = *(const s16x8*)&Kq_[(32 + l15) * 64 + ((32 + quad * 8) ^ swr)];    \
    kb3 = *(const s16x8*)&Kq_[(48 + l15) * 64 + ((32 + quad * 8) ^ swr)];    \
  } while (0)

#define QK_MFMA(S0_, S1_, S2_, S3_) do {                                     \
    f32x4 z_ = {};                                                           \
    z_ = mfma_bf16(qf0, ka0, z_); S0_ = mfma_bf16(qf1, kb0, z_);             \
    z_ = (f32x4){};                                                          \
    z_ = mfma_bf16(qf0, ka1, z_); S1_ = mfma_bf16(qf1, kb1, z_);             \
    z_ = (f32x4){};                                                          \
    z_ = mfma_bf16(qf0, ka2, z_); S2_ = mfma_bf16(qf1, kb2, z_);             \
    z_ = (f32x4){};                                                          \
    z_ = mfma_bf16(qf0, ka3, z_); S3_ = mfma_bf16(qf1, kb3, z_);             \
  } while (0)

#define SMAXPV(J, S0_, S1_, S2_, S3_) do {                                   \
    if ((J) == nt - 1) {  /* diagonal tile only */                           \
      _Pragma("unroll") for (int reg = 0; reg < 4; ++reg) {                  \
        const int qrow_ = qb + (w << 4) + quad * 4 + reg;                    \
        const int k0_ = ((J) << 6) + l15;                                    \
        if (k0_ +  0 > qrow_) S0_[reg] = -1e30f;                             \
        if (k0_ + 16 > qrow_) S1_[reg] = -1e30f;                             \
        if (k0_ + 32 > qrow_) S2_[reg] = -1e30f;                             \
        if (k0_ + 48 > qrow_) S3_[reg] = -1e30f;                             \
      }                                                                      \
    }                                                                        \
    float mx_[4];                                                            \
    _Pragma("unroll") for (int reg = 0; reg < 4; ++reg)                      \
      mx_[reg] = fmaxf(fmaxf(S0_[reg], S1_[reg]), fmaxf(S2_[reg], S3_[reg]));\
    _Pragma("unroll") for (int off = 1; off < 16; off <<= 1)                 \
      _Pragma("unroll") for (int reg = 0; reg < 4; ++reg)                    \
        mx_[reg] = fmaxf(mx_[reg], __shfl_xor(mx_[reg], off, 64));           \
    bool up_ = false;                                                        \
    _Pragma("unroll") for (int reg = 0; reg < 4; ++reg)                      \
      up_ = up_ || (mx_[reg] > m_i[reg] + 8.f);                              \
    if (__any(up_)) {  /* defer-max (T13): rescale only on real growth */    \
      _Pragma("unroll") for (int reg = 0; reg < 4; ++reg) {                  \
        const float nm_ = fmaxf(m_i[reg], mx_[reg]);                         \
        const float al_ = __expf(m_i[reg] - nm_);                            \
        m_i[reg] = nm_; l_p[reg] *= al_;                                     \
        o[0][reg] *= al_; o[1][reg] *= al_;                                  \
        o[2][reg] *= al_; o[3][reg] *= al_;                                  \
      }                                                                      \
    }                                                                        \
    _Pragma("unroll") for (int reg = 0; reg < 4; ++reg) {                    \
      const float e0_ = __expf(S0_[reg] - m_i[reg]);                         \
      const float e1_ = __expf(S1_[reg] - m_i[reg]);                         \
      const float e2_ = __expf(S2_[reg] - m_i[reg]);                         \
      const float e3_ = __expf(S3_[reg] - m_i[reg]);                         \
      l_p[reg] += e0_ + e1_ + e2_ + e3_;                                     \
      const int row_ = quad * 4 + reg;                                       \
      bf16* pr_ = &Ps[w][row_ * 64];                                         \
      const int sx_ = (row_ & 7) << 3;                                       \
      pr_[( 0 + l15) ^ sx_] = __float2bfloat16(e0_);                         \
      pr_[(16 + l15) ^ sx_] = __float2bfloat16(e1_);                         \
      pr_[(32 + l15) ^ sx_] = __float2bfloat16(e2_);                         \
      pr_[(48 + l15) ^ sx_] = __float2bfloat16(e3_);                         \
    }                                                                        \
    {                                                                        \
      const bf16* Vc_ = Vt[(J) & 1];                                         \
      _Pragma("unroll") for (int ks = 0; ks < 2; ++ks) {                     \
        const s16x8 pf_ =                                                    \
            *(const s16x8*)&Ps[w][l15 * 64 + ((ks * 32 + quad * 8) ^ swr)];  \
        _Pragma("unroll") for (int ni = 0; ni < 4; ++ni) {                   \
          const s16x8 vf_ = *(const s16x8*)                                  \
              &Vc_[(ni * 16 + l15) * 64 + ((ks * 32 + quad * 8) ^ swr)];     \
          o[ni] = mfma_bf16(pf_, vf_, o[ni]);                                \
        }                                                                    \
      }                                                                      \
    }                                                                        \
  } while (0)

#define BODY(KT, SO0, SO1, SO2, SO3, SN0, SN1, SN2, SN3) do {                \
    WRITEKV(KT);                                                             \
    BAR_SYNC();                                                              \
    if ((KT) + 1 < nt) ISSUE((KT) + 1);                                      \
    QK_LOAD(KT);                                                             \
    QK_MFMA(SN0, SN1, SN2, SN3);                                             \
    SMAXPV((KT) - 1, SO0, SO1, SO2, SO3);                                    \
    BAR_SYNC();                                                              \
  } while (0)

__global__ __launch_bounds__(256, 2) void flash_attn(
    const bf16* __restrict__ Q, const bf16* __restrict__ Kk,
    const bf16* __restrict__ V, bf16* __restrict__ O) {
  const int bxp = blockIdx.x;                 // 0..15: q-tile pair id
  const int h = blockIdx.y, b = blockIdx.z;
  const int t = threadIdx.x, w = t >> 6, l = t & 63;
  const int l15 = l & 15, quad = l >> 4;
  __shared__ __align__(16) bf16 Ks[2][64 * 64];    // [buf][key][d] swizzled
  __shared__ __align__(16) bf16 Vt[2][64 * 64];    // [buf][d][key] swizzled
  __shared__ __align__(16) bf16 Ps[4][16 * 64];    // per-wave P, swizzled

  // K staging: linear global chunk; swizzle applied at ds_write dest.
  const int krow = t >> 3;                    // 0..31
  const int kchunk = (t & 7) ^ (krow & 7);    // swizzled LDS chunk
  const bf16* Kg  = Kk + (size_t)(b * S_ + krow) * D_ + h * HD_ + ((t & 7) << 3);
  const bf16* Kg2 = Kg + (size_t)32 * D_;
  const int vk = t & 63, vd = w << 4;
  const bf16* Vg = V + (size_t)(b * S_ + vk) * D_ + h * HD_ + vd;
  const int swr = (l15 & 7) << 3;             // read-side xor (elements)

  s16x8 kr0, kr1, vr0, vr1;                   // staging regs (1 tile)
  s16x8 ka0, ka1, ka2, ka3, kb0, kb1, kb2, kb3;  // K fragment regs

#pragma unroll 1
  for (int ph = 0; ph < 2; ++ph) {
    const int qt = ph ? (S_ / 64 - 1 - bxp) : bxp;
    const int qb = qt << 6;
    const int nt = qt + 1;

    __syncthreads();   // protect LDS reuse across phases (full drain, 2x total)

    const bf16* qp =
        Q + (size_t)(b * S_ + qb + (w << 4) + l15) * D_ + h * HD_ + quad * 8;
    const s16x8 qf0 = *(const s16x8*)qp;
    const s16x8 qf1 = *(const s16x8*)(qp + 32);

    f32x4 o[4] = {};
    float m_i[4], l_p[4];
#pragma unroll
    for (int r = 0; r < 4; ++r) { m_i[r] = -1e30f; l_p[r] = 0.f; }

    f32x4 sA0, sA1, sA2, sA3, sB0, sB1, sB2, sB3;

    // ---- prologue: tile 0 ----
    ISSUE(0);
    WRITEKV(0);                  // counted vmcnt waits for kr/vr (cold, once)
    BAR_SYNC();
    if (nt > 1) ISSUE(1);
    QK_LOAD(0);
    QK_MFMA(sA0, sA1, sA2, sA3);
    BAR_SYNC();

    // ---- main loop: 2-stage score pipeline, hand-unrolled ping-pong ----
    int kt = 1;
    for (; kt + 1 < nt; kt += 2) {
      BODY(kt,     sA0, sA1, sA2, sA3, sB0, sB1, sB2, sB3);
      BODY(kt + 1, sB0, sB1, sB2, sB3, sA0, sA1, sA2, sA3);
    }
    if (kt < nt) {
      BODY(kt, sA0, sA1, sA2, sA3, sB0, sB1, sB2, sB3);
      SMAXPV(nt - 1, sB0, sB1, sB2, sB3);
    } else {
      SMAXPV(nt - 1, sA0, sA1, sA2, sA3);
    }

    // ---- epilogue: deferred l reduction + O write ----
    float inv[4];
#pragma unroll
    for (int off = 1; off < 16; off <<= 1)
#pragma unroll
      for (int reg = 0; reg < 4; ++reg)
        l_p[reg] += __shfl_xor(l_p[reg], off, 64);
#pragma unroll
    for (int reg = 0; reg < 4; ++reg) inv[reg] = 1.f / l_p[reg];

#pragma unroll
    for (int reg = 0; reg < 4; ++reg) {
      const int row = b * S_ + qb + (w << 4) + quad * 4 + reg;
      bf16* op = O + (size_t)row * D_ + h * HD_ + l15;
#pragma unroll
      for (int ni = 0; ni < 4; ++ni)
        op[ni * 16] = __float2bfloat16(o[ni][reg] * inv[reg]);
    }
  }
}

// ---------------------------------------------------------------------------
// LN1 (MODE 0): h1 = LN(x_f32 + y1_bf16) -> bf16.
// LN2 (MODE 1): out = LN(X + PA/PB partial) -> fp32 in place (X=out holds
//               K-half-0 + bias + resid; PA/PB hold K-half-1 partial).
// One block per 1024-col row.
// ---------------------------------------------------------------------------
template <int MODE>   // 0: LN1, 1: LN2
__global__ __launch_bounds__(256) void add_ln(
    const float* __restrict__ X, const bf16* __restrict__ Y,
    const float* __restrict__ PA, const float* __restrict__ PB,
    const float* __restrict__ g, const float* __restrict__ be,
    void* Out) {
  const int row = blockIdx.x, t = threadIdx.x;
  const size_t base = (size_t)row * D_ + t * 4;
  const float* P = (MODE == 1)
      ? ((row < 2048) ? PA + base : PB + (base - (size_t)2048 * D_))
      : nullptr;
  float v[4];
  float s = 0.f, q = 0.f;
#pragma unroll
  for (int i = 0; i < 4; ++i) {
    v[i] = X[base + i];
    if (MODE == 0) v[i] += b2f(*(const short*)&Y[base + i]);
    else           v[i] += P[i];
    s += v[i];
    q += v[i] * v[i];
  }
#pragma unroll
  for (int off = 32; off; off >>= 1) {
    s += __shfl_down(s, off, 64);
    q += __shfl_down(q, off, 64);
  }
  __shared__ float rs[4], rq[4];
  const int w = t >> 6, l = t & 63;
  if (l == 0) { rs[w] = s; rq[w] = q; }
  __syncthreads();
  s = rs[0] + rs[1] + rs[2] + rs[3];
  q = rq[0] + rq[1] + rq[2] + rq[3];
  const float mu = s * (1.f / D_);
  const float var = q * (1.f / D_) - mu * mu;
  const float rstd = rsqrtf(var + 1e-5f);
#pragma unroll
  for (int i = 0; i < 4; ++i) {
    const float r = (v[i] - mu) * rstd * g[t * 4 + i] + be[t * 4 + i];
    if (MODE == 0) ((bf16*)Out)[base + i] = __float2bfloat16(r);
    else           ((float*)Out)[base + i] = r;
  }
}

extern "C" void kernel_launch(void* const* d_in, const int* in_sizes, int n_in,
                              void* d_out, int out_size, void* d_ws, size_t ws_size,
                              hipStream_t stream) {
  const float* x     = (const float*)d_in[0];
  const float* qkv_b = (const float*)d_in[2];
  const float* out_b = (const float*)d_in[4];
  const float* b1    = (const float*)d_in[6];
  const float* b2    = (const float*)d_in[8];
  const float* l1w   = (const float*)d_in[9];
  const float* l1b   = (const float*)d_in[10];
  const float* l2w   = (const float*)d_in[11];
  const float* l2b   = (const float*)d_in[12];

  float* out    = (float*)d_out;
  float* kcache = out + (size_t)M_ * D_;
  float* vcache = kcache + (size_t)M_ * D_;

  // ws (bf16 elems). High-water 36M elems = 72 MB (<75 MB established safe).
  //  [0,4M)   xc      -> attnb (after QKV) -> pA fp32 partial (after outproj)
  //  [4,7M)   wqkv    -> h1 (after out-proj; h1 spans [4,8M))
  //  [7,8M)   wout
  //  [8,12M)  w1c
  //  [12,16M) w2c
  //  [16,20M) qbuf    -> y1 (after flash) -> pB fp32 partial (after ln1)
  //  [20,24M) kb      -> ffb (after flash; full ffb spans [20,36M))
  //  [24,28M) vb
  bf16* ws    = (bf16*)d_ws;
  bf16* xc    = ws;
  bf16* attnb = ws;
  bf16* wqkv  = ws + 4 * MEG;
  bf16* h1    = ws + 4 * MEG;
  bf16* wout  = ws + 7 * MEG;
  bf16* w1c   = ws + 8 * MEG;
  bf16* w2c   = ws + 12 * MEG;
  bf16* qbuf  = ws + 16 * MEG;
  bf16* y1    = ws + 16 * MEG;
  bf16* kb    = ws + 20 * MEG;
  bf16* ffb   = ws + 20 * MEG;
  bf16* vb    = ws + 24 * MEG;
  float* pA   = (float*)ws;               // rows 0..2047  K-half-1 partial
  float* pB   = (float*)(ws + 16 * MEG);  // rows 2048..4095

  const dim3 blk(256);

  // all 5 fp32->bf16 conversions in one dispatch
  CvtArgs ca;
  ca.src[0] = x;                    ca.dst[0] = xc;   ca.n[0] = M_ * D_;
  ca.src[1] = (const float*)d_in[1]; ca.dst[1] = wqkv; ca.n[1] = 3 * D_ * D_;
  ca.src[2] = (const float*)d_in[3]; ca.dst[2] = wout; ca.n[2] = D_ * D_;
  ca.src[3] = (const float*)d_in[5]; ca.dst[3] = w1c;  ca.n[3] = FFD_ * D_;
  ca.src[4] = (const float*)d_in[7]; ca.dst[4] = w2c;  ca.n[4] = D_ * FFD_;
  cvt_f2b_multi<<<dim3((M_ * D_ + 2047) / 2048, 5), blk, 0, stream>>>(ca);

  // QKV: q (pre-scaled 0.125) -> qbuf bf16; k/v->fp32 caches + bf16 ws copies.
  gemm_bt<3><<<dim3(3 * D_ / 128, M_ / 128), blk, 0, stream>>>(
      xc, wqkv, qkv_b, qbuf, nullptr, kcache, kb, vcache, vb, nullptr,
      M_, 3 * D_, D_);
  flash_attn<<<dim3(S_ / 128, H_, B_), blk, 0, stream>>>(qbuf, kb, vb, attnb);
  // out-proj -> y1 bf16 (overwrites dead qbuf)
  gemm_bt<0><<<dim3(D_ / 128, M_ / 128), blk, 0, stream>>>(
      attnb, wout, out_b, y1, nullptr, nullptr, nullptr, nullptr, nullptr,
      nullptr, M_, D_, D_);
  // h1 = LN(x + y1) -> bf16 (overwrites dead wqkv)
  add_ln<0><<<dim3(M_), blk, 0, stream>>>(x, y1, nullptr, nullptr, l1w, l1b, h1);
  // MLP full-M: MLP1 -> ffb [20,36M); MLP2 split-K=2:
  // z=0 K-half-0 + bias + resid -> out; z=1 K-half-1 raw -> pA/pB.
  gemm_bt<1><<<dim3(FFD_ / 128, M_ / 128), blk, 0, stream>>>(
      h1, w1c, b1, ffb, nullptr, nullptr, nullptr, nullptr, nullptr,
      nullptr, M_, FFD_, D_);
  gemm_bt<2><<<dim3(D_ / 128, M_ / 128, 2), blk, 0, stream>>>(
      ffb, w2c, b2, nullptr, out, pA, nullptr, pB, nullptr,
      h1, M_, D_, FFD_);
  // out = LN(out + partial) in place, fp32.
  add_ln<1><<<dim3(M_), blk, 0, stream>>>(out, nullptr, pA, pB, l2w, l2b, out);
}